// Round 11
// baseline (4332.678 us; speedup 1.0000x reference)
//
#include <hip/hip_runtime.h>
#include <hip/hip_bf16.h>
#include <stdint.h>

#define VV 32000
#define HH 128
#define BB 8
#define SS 512
#define NNODE 50000
#define NEDGE 600000

typedef __attribute__((ext_vector_type(8))) short s16x8;
typedef __attribute__((ext_vector_type(4))) float f32x4;

// ---------------- embedding gather + encoder input-gate GEMM ----------------
__global__ __launch_bounds__(256) void xg_enc_kernel(
    const int* __restrict__ jin, const float* __restrict__ emb,
    const float* __restrict__ Wih, const float* __restrict__ bvec,
    float* __restrict__ xg)
{
  __shared__ __align__(16) float arow[8][128];
  const int tid = threadIdx.x, blk = blockIdx.x;
  {
    int r = tid >> 5, c = (tid & 31) << 2;
    int tok = jin[blk*8 + r];
    *(float4*)&arow[r][c] = *(const float4*)&emb[(size_t)tok*HH + c];
  }
  __syncthreads();
  const int g0 = tid * 2;
  const float* w0 = Wih + (size_t)g0*HH;
  const float* w1 = w0 + HH;
  float acc0[8], acc1[8];
  #pragma unroll
  for (int r=0;r<8;r++){ acc0[r]=0.f; acc1[r]=0.f; }
  for (int k=0;k<HH;k+=4) {
    float4 wa = *(const float4*)&w0[k];
    float4 wb = *(const float4*)&w1[k];
    #pragma unroll
    for (int r=0;r<8;r++) {
      float4 av = *(const float4*)&arow[r][k];
      acc0[r] += av.x*wa.x + av.y*wa.y + av.z*wa.z + av.w*wa.w;
      acc1[r] += av.x*wb.x + av.y*wb.y + av.z*wb.z + av.w*wb.w;
    }
  }
  float bb0 = bvec[g0], bb1 = bvec[g0+1];
  #pragma unroll
  for (int r=0;r<8;r++) {
    size_t row = (size_t)blk*8 + r;
    xg[row*512 + g0]     = acc0[r] + bb0;
    xg[row*512 + g0 + 1] = acc1[r] + bb1;
  }
}

// ---------------- W_hh layout prep: W[512][128] -> Wc[k][g] (float4 chunks) ----
__global__ __launch_bounds__(256) void wprep_kernel(const float* __restrict__ W,
                                                    f32x4* __restrict__ Wc) {
  int i = blockIdx.x*256 + threadIdx.x;      // 512*32 = 16384 chunks
  if (i >= 512*32) return;
  int g = i & 511, k = i >> 9;
  Wc[k*512 + g] = *(const f32x4*)&W[g*HH + 4*k];
}

// ---------------- LSTM scan: TWO batches per workgroup (1024 thr, 16 waves) ----
// Round-10's falsification: weight-fetch pattern is irrelevant (coalesced ==
// row-major == 447us). The wall is UNHIDDEN LATENCY at 2 waves/SIMD. Fix:
// pack 2 independent batches per block -> 4 waves/SIMD, stalls of one half
// fill with the other half's issue. Arithmetic identical to round 4/10 ->
// absmax must stay exactly 7.450581e-09.
// Half sub = tid>>9 handles batch b = blockIdx*2+sub; inner layout unchanged:
// thread t (of 512) owns gate row t (i:0-127, f:128-255, g:256-383, o:384-511).
template<int MODE>
__global__ __launch_bounds__(1024, 4) void lstm_scan_kernel(
    const float* __restrict__ xg, const f32x4* __restrict__ Wc,
    float* __restrict__ hmean,
    __hip_bfloat16* __restrict__ ahi, __hip_bfloat16* __restrict__ alo)
{
  __shared__ __align__(16) float h_s[2][128];
  __shared__ float act_s[2][512];
  const int sub = threadIdx.x >> 9;            // which batch of the pair
  const int tid = threadIdx.x & 511;           // role within the batch
  const int b = blockIdx.x*2 + sub;

  const f32x4* wbase = Wc + tid;               // Wc[k][tid]: coalesced stream

  float xv;
  const float* xgrow = nullptr;
  if (MODE==1) {
    xv = xg[b*512 + tid];
  } else {
    xgrow = xg + (size_t)b*SS*512;
    xv = xgrow[tid];
  }
  if (tid < 128) h_s[sub][tid] = 0.f;
  float cstate = 0.f, hsum = 0.f;
  __syncthreads();

  for (int t=0;t<SS;t++) {
    float nxv = 0.f;
    if (MODE==0) {                  // prefetch next x_t
      int tn = (t < SS-1) ? (t+1) : t;
      nxv = xgrow[(size_t)tn*512 + tid];
    }
    float a0=0.f,a1=0.f,a2=0.f,a3=0.f;
    #pragma unroll
    for (int k=0;k<32;k++) {
      f32x4 wv = wbase[k*512];                 // contiguous 1KB per wave-instr
      f32x4 hv = *(const f32x4*)&h_s[sub][k*4];// wave-uniform -> LDS broadcast
      a0 += wv.x*hv.x; a1 += wv.y*hv.y;
      a2 += wv.z*hv.z; a3 += wv.w*hv.w;
    }
    float s = (a0+a1)+(a2+a3) + xv;
    int gid = tid >> 7;                        // wave-uniform gate id
    float act = (gid==2) ? tanhf(s) : 1.0f/(1.0f+expf(-s));
    act_s[sub][tid] = act;
    __syncthreads();
    if (tid < 128) {
      float i_ = act_s[sub][tid],     f_ = act_s[sub][128+tid];
      float g_ = act_s[sub][256+tid], o_ = act_s[sub][384+tid];
      cstate = f_*cstate + i_*g_;
      float hh = o_*tanhf(cstate);
      h_s[sub][tid] = hh;
      if (MODE==0) {
        hsum += hh;
      } else {
        size_t row = (size_t)b*SS + t;
        __hip_bfloat16 hi = __float2bfloat16(hh);
        float rem = hh - __bfloat162float(hi);
        ahi[row*HH + tid] = hi;
        alo[row*HH + tid] = __float2bfloat16(rem);
      }
    }
    if (MODE==0) xv = nxv;
    __syncthreads();
  }
  if (MODE==0 && tid < 128) hmean[b*HH + tid] = hsum * (1.0f/512.0f);
}

// ---------------- graph branch (collapsed to scalar edge passes) ----------------
__global__ __launch_bounds__(256) void edge_deg_kernel(const int* __restrict__ dst, float* __restrict__ deg) {
  int i = blockIdx.x*256 + threadIdx.x;
  if (i < NEDGE) atomicAdd(&deg[dst[i]], 1.0f);
}
__global__ __launch_bounds__(256) void node_dinv_kernel(const float* __restrict__ deg, float* __restrict__ dinv) {
  int n = blockIdx.x*256 + threadIdx.x;
  if (n < NNODE) dinv[n] = 1.0f / sqrtf(deg[n] + 1.0f);
}
__global__ __launch_bounds__(256) void edge_s1_kernel(const int* __restrict__ src, const int* __restrict__ dst,
    const float* __restrict__ dinv, float* __restrict__ s1) {
  int i = blockIdx.x*256 + threadIdx.x;
  if (i < NEDGE) atomicAdd(&s1[src[i]], dinv[dst[i]]);
}
__global__ __launch_bounds__(256) void node_c_kernel(const float* __restrict__ dinv, const float* __restrict__ s1,
    float* __restrict__ cc, float* __restrict__ csum) {
  __shared__ float red[256];
  int tid = threadIdx.x;
  int n = blockIdx.x*256 + tid;
  float v = 0.f;
  if (n < NNODE) { float d = dinv[n]; v = d*s1[n] + d*d; cc[n] = v; }
  red[tid] = v; __syncthreads();
  for (int sfl=128; sfl>0; sfl>>=1) { if (tid < sfl) red[tid] += red[tid+sfl]; __syncthreads(); }
  if (tid==0) atomicAdd(csum, red[0]);
}
__global__ __launch_bounds__(256) void edge_s2_kernel(const int* __restrict__ src, const int* __restrict__ dst,
    const float* __restrict__ dinv, const float* __restrict__ cc, float* __restrict__ s2) {
  int i = blockIdx.x*256 + threadIdx.x;
  if (i < NEDGE) { int d = dst[i]; atomicAdd(&s2[src[i]], cc[d]*dinv[d]); }
}
__global__ __launch_bounds__(256) void node_e_kernel(const float* __restrict__ dinv, const float* __restrict__ s2,
    const float* __restrict__ cc, float* __restrict__ ee) {
  int n = blockIdx.x*256 + threadIdx.x;
  if (n < NNODE) { float d = dinv[n]; ee[n] = d*s2[n] + cc[n]*d*d; }
}
__global__ __launch_bounds__(256) void gvec_kernel(const int* __restrict__ nids, const float* __restrict__ emb,
    const float* __restrict__ ee, float* __restrict__ gvec) {
  __shared__ float red[256];
  int tid = threadIdx.x;
  int j = tid & 127, sub = tid >> 7;
  float acc = 0.f;
  for (int n = blockIdx.x*2 + sub; n < NNODE; n += gridDim.x*2) {
    acc += ee[n] * emb[(size_t)nids[n]*HH + j];
  }
  red[tid] = acc; __syncthreads();
  if (tid < 128) atomicAdd(&gvec[j], red[tid] + red[tid+128]);
}
__global__ void graph_final_kernel(const float* __restrict__ gvec, const float* __restrict__ csum,
    const float* __restrict__ W1, const float* __restrict__ b1,
    const float* __restrict__ W2, const float* __restrict__ b2, float* __restrict__ mvec) {
  __shared__ float gs[128], v1[128];
  int j = threadIdx.x;
  gs[j] = gvec[j];
  __syncthreads();
  float a = 0.f;
  for (int k=0;k<128;k++) a += gs[k]*W1[j*128+k];
  v1[j] = a + csum[0]*b1[j];
  __syncthreads();
  float a2 = 0.f;
  for (int k=0;k<128;k++) a2 += v1[k]*W2[j*128+k];
  mvec[j] = a2 * (1.0f/(float)NNODE) + b2[j];
}

// ---------------- fusion ----------------
__global__ __launch_bounds__(512) void fusion_kernel(const float* __restrict__ hmean, const float* __restrict__ mvec,
    const float* __restrict__ Wf, const float* __restrict__ bfv,
    const float* __restrict__ Wihd, const float* __restrict__ bd, float* __restrict__ xgdec)
{
  __shared__ float comb[256];
  __shared__ float fus[128];
  int b = blockIdx.x, tid = threadIdx.x;
  if (tid < 128) comb[tid] = hmean[b*128 + tid];
  else if (tid < 256) comb[tid] = mvec[tid - 128];
  __syncthreads();
  if (tid < 128) {
    float a = 0.f;
    for (int k=0;k<256;k++) a += comb[k]*Wf[tid*256+k];
    fus[tid] = a + bfv[tid];
  }
  __syncthreads();
  float a = 0.f;
  for (int k=0;k<128;k++) a += fus[k]*Wihd[tid*128+k];
  xgdec[b*512 + tid] = a + bd[tid];
}

// ---------------- split fp32 -> (bf16 hi, bf16 lo) ----------------
__global__ __launch_bounds__(256) void split_bf16_kernel(const float* __restrict__ x,
    __hip_bfloat16* __restrict__ hi, __hip_bfloat16* __restrict__ lo, int n4) {
  int i = blockIdx.x*256 + threadIdx.x;
  if (i >= n4) return;
  float4 v = *(const float4*)&x[i*4];
  float vv[4] = {v.x, v.y, v.z, v.w};
  #pragma unroll
  for (int k=0;k<4;k++) {
    __hip_bfloat16 h = __float2bfloat16(vv[k]);
    hi[i*4+k] = h;
    lo[i*4+k] = __float2bfloat16(vv[k] - __bfloat162float(h));
  }
}

// ---------------- output GEMM: [4096,128] @ Wo^T -> [4096,32000], split-bf16 MFMA ----------------
// Operand-swapped MFMA: mfma(b_frag, a_frag) computes (AB)^T in the standard
// C/D layout -> 4 consecutive cols per lane -> dwordx4 stores.
__global__ __launch_bounds__(256) void out_gemm_kernel(
    const __hip_bfloat16* __restrict__ Ahi, const __hip_bfloat16* __restrict__ Alo,
    const __hip_bfloat16* __restrict__ Bhi, const __hip_bfloat16* __restrict__ Blo,
    const float* __restrict__ bo, float* __restrict__ out)
{
  __shared__ __align__(16) short smem[4*64*128];   // 4 planes x 16KB = 64KB
  const int tid = threadIdx.x;
  const int bid = blockIdx.x;
  const int mblk = bid & 63;
  const int nblk = bid >> 6;
  const short* srcs[4] = {
    (const short*)Ahi + (size_t)mblk*64*HH,
    (const short*)Alo + (size_t)mblk*64*HH,
    (const short*)Bhi + (size_t)nblk*64*HH,
    (const short*)Blo + (size_t)nblk*64*HH };
  const int wuni  = (tid >> 6) * 1024;
  const int lbyte = (tid & 63) * 16;
  #pragma unroll
  for (int p=0;p<4;p++) {
    #pragma unroll
    for (int it=0; it<4; it++) {
      int off  = it*4096 + wuni + lbyte;
      int row  = off >> 8;
      int soff = off ^ ((row & 15) << 4);
      __builtin_amdgcn_global_load_lds(
        (const __attribute__((address_space(1))) void*)((const char*)srcs[p] + soff),
        (__attribute__((address_space(3))) void*)((char*)smem + p*16384 + it*4096 + wuni),
        16, 0, 0);
    }
  }
  __syncthreads();

  const int lane = tid & 63;
  const int wid  = tid >> 6;
  const int wm = wid >> 1, wn = wid & 1;
  const int l15 = lane & 15, l4 = lane >> 4;

  f32x4 acc[2][2] = {};
  #pragma unroll
  for (int s=0;s<4;s++) {
    s16x8 ah[2], al[2], bh[2], bl[2];
    #pragma unroll
    for (int q=0;q<2;q++) {
      int ra   = wm*32 + q*16 + l15;
      int offa = (ra*256 + s*64 + l4*16) ^ ((ra & 15) << 4);
      ah[q] = *(const s16x8*)((const char*)smem + offa);
      al[q] = *(const s16x8*)((const char*)smem + 16384 + offa);
      int rb   = wn*32 + q*16 + l15;
      int offb = (rb*256 + s*64 + l4*16) ^ ((rb & 15) << 4);
      bh[q] = *(const s16x8*)((const char*)smem + 32768 + offb);
      bl[q] = *(const s16x8*)((const char*)smem + 49152 + offb);
    }
    #pragma unroll
    for (int mi=0;mi<2;mi++) {
      #pragma unroll
      for (int ni=0;ni<2;ni++) {
        acc[mi][ni] = __builtin_amdgcn_mfma_f32_16x16x32_bf16(bh[ni], ah[mi], acc[mi][ni], 0,0,0);
        acc[mi][ni] = __builtin_amdgcn_mfma_f32_16x16x32_bf16(bl[ni], ah[mi], acc[mi][ni], 0,0,0);
        acc[mi][ni] = __builtin_amdgcn_mfma_f32_16x16x32_bf16(bh[ni], al[mi], acc[mi][ni], 0,0,0);
      }
    }
  }
  const int m0 = mblk*64 + wm*32;
  const int n0 = nblk*64 + wn*32;
  #pragma unroll
  for (int mi=0;mi<2;mi++) {
    int row = m0 + mi*16 + l15;                  // swapped layout: l15 = M-row
    #pragma unroll
    for (int ni=0;ni<2;ni++) {
      int colb = n0 + ni*16 + l4*4;              // 4 consecutive cols per lane
      f32x4 bv = *(const f32x4*)&bo[colb];
      f32x4 o = acc[mi][ni] + bv;
      *(f32x4*)&out[(size_t)row*VV + colb] = o;  // one dwordx4 store
    }
  }
}

// ---------------- launch ----------------
extern "C" void kernel_launch(void* const* d_in, const int* in_sizes, int n_in,
                              void* d_out, int out_size, void* d_ws, size_t ws_size,
                              hipStream_t stream)
{
  (void)in_sizes; (void)n_in; (void)out_size; (void)ws_size;
  const int*   jin   = (const int*)d_in[0];
  const int*   nids  = (const int*)d_in[1];
  const int*   esrc  = (const int*)d_in[2];
  const int*   edst  = esrc + NEDGE;
  const float* emb   = (const float*)d_in[3];
  const float* WihE  = (const float*)d_in[4];
  const float* WhhE  = (const float*)d_in[5];
  const float* bE    = (const float*)d_in[6];
  const float* W1    = (const float*)d_in[7];
  const float* b1    = (const float*)d_in[8];
  const float* W2    = (const float*)d_in[9];
  const float* b2    = (const float*)d_in[10];
  const float* Wf    = (const float*)d_in[11];
  const float* bfv   = (const float*)d_in[12];
  const float* WihD  = (const float*)d_in[13];
  const float* WhhD  = (const float*)d_in[14];
  const float* bD    = (const float*)d_in[15];
  const float* Wo    = (const float*)d_in[16];
  const float* bo    = (const float*)d_in[17];
  float* out = (float*)d_out;

  char* ws = (char*)d_ws;
  size_t off = 0;
  auto alloc = [&](size_t bytes) { size_t o = off; off = (off + bytes + 255) & ~(size_t)255; return o; };

  float* deg  = (float*)(ws + alloc(NNODE*4));
  float* s1   = (float*)(ws + alloc(NNODE*4));
  float* s2   = (float*)(ws + alloc(NNODE*4));
  float* gvec = (float*)(ws + alloc(128*4));
  float* csum = (float*)(ws + alloc(4));
  size_t zero_bytes = off;
  float* dinv = (float*)(ws + alloc(NNODE*4));
  float* cc   = (float*)(ws + alloc(NNODE*4));
  float* ee   = (float*)(ws + alloc(NNODE*4));
  float* mvec = (float*)(ws + alloc(128*4));
  float* hmean= (float*)(ws + alloc(BB*HH*4));
  float* xgdec= (float*)(ws + alloc(BB*512*4));
  f32x4* WcE  = (f32x4*)(ws + alloc((size_t)512*128*4));
  f32x4* WcD  = (f32x4*)(ws + alloc((size_t)512*128*4));
  float* xgenc= (float*)(ws + alloc((size_t)BB*SS*512*4));
  __hip_bfloat16* Ahi = (__hip_bfloat16*)(ws + alloc((size_t)BB*SS*HH*2));
  __hip_bfloat16* Alo = (__hip_bfloat16*)(ws + alloc((size_t)BB*SS*HH*2));
  __hip_bfloat16* Bhi = (__hip_bfloat16*)(ws + alloc((size_t)VV*HH*2));
  __hip_bfloat16* Blo = (__hip_bfloat16*)(ws + alloc((size_t)VV*HH*2));

  hipMemsetAsync(ws, 0, zero_bytes, stream);

  // weight layout prep (tiny)
  wprep_kernel<<<dim3(64), dim3(256), 0, stream>>>(WhhE, WcE);
  wprep_kernel<<<dim3(64), dim3(256), 0, stream>>>(WhhD, WcD);

  // sequence branch
  xg_enc_kernel<<<dim3((BB*SS)/8), dim3(256), 0, stream>>>(jin, emb, WihE, bE, xgenc);
  lstm_scan_kernel<0><<<dim3(BB/2), dim3(1024), 0, stream>>>(xgenc, WcE, hmean, nullptr, nullptr);

  // graph branch (collapsed)
  edge_deg_kernel<<<dim3((NEDGE+255)/256), dim3(256), 0, stream>>>(edst, deg);
  node_dinv_kernel<<<dim3((NNODE+255)/256), dim3(256), 0, stream>>>(deg, dinv);
  edge_s1_kernel<<<dim3((NEDGE+255)/256), dim3(256), 0, stream>>>(esrc, edst, dinv, s1);
  node_c_kernel<<<dim3((NNODE+255)/256), dim3(256), 0, stream>>>(dinv, s1, cc, csum);
  edge_s2_kernel<<<dim3((NEDGE+255)/256), dim3(256), 0, stream>>>(esrc, edst, dinv, cc, s2);
  node_e_kernel<<<dim3((NNODE+255)/256), dim3(256), 0, stream>>>(dinv, s2, cc, ee);
  gvec_kernel<<<dim3(256), dim3(256), 0, stream>>>(nids, emb, ee, gvec);
  graph_final_kernel<<<dim3(1), dim3(128), 0, stream>>>(gvec, csum, W1, b1, W2, b2, mvec);

  // fusion + decoder
  fusion_kernel<<<dim3(BB), dim3(512), 0, stream>>>(hmean, mvec, Wf, bfv, WihD, bD, xgdec);
  lstm_scan_kernel<1><<<dim3(BB/2), dim3(1024), 0, stream>>>(xgdec, WcD, nullptr, Ahi, Alo);

  // output projection
  split_bf16_kernel<<<dim3((VV*HH/4+255)/256), dim3(256), 0, stream>>>(Wo, Bhi, Blo, VV*HH/4);
  out_gemm_kernel<<<dim3(64*(VV/64)), dim3(256), 0, stream>>>(Ahi, Alo, Bhi, Blo, bo, out);
}

// Round 12
// 3202.343 us; speedup vs baseline: 1.3530x; 1.3530x over previous
//
#include <hip/hip_runtime.h>
#include <hip/hip_bf16.h>
#include <stdint.h>

#define VV 32000
#define HH 128
#define BB 8
#define SS 512
#define NNODE 50000
#define NEDGE 600000

typedef __attribute__((ext_vector_type(8))) short s16x8;
typedef __attribute__((ext_vector_type(4))) float f32x4;

// ---------------- embedding gather + encoder input-gate GEMM ----------------
__global__ __launch_bounds__(256) void xg_enc_kernel(
    const int* __restrict__ jin, const float* __restrict__ emb,
    const float* __restrict__ Wih, const float* __restrict__ bvec,
    float* __restrict__ xg)
{
  __shared__ __align__(16) float arow[8][128];
  const int tid = threadIdx.x, blk = blockIdx.x;
  {
    int r = tid >> 5, c = (tid & 31) << 2;
    int tok = jin[blk*8 + r];
    *(float4*)&arow[r][c] = *(const float4*)&emb[(size_t)tok*HH + c];
  }
  __syncthreads();
  const int g0 = tid * 2;
  const float* w0 = Wih + (size_t)g0*HH;
  const float* w1 = w0 + HH;
  float acc0[8], acc1[8];
  #pragma unroll
  for (int r=0;r<8;r++){ acc0[r]=0.f; acc1[r]=0.f; }
  for (int k=0;k<HH;k+=4) {
    float4 wa = *(const float4*)&w0[k];
    float4 wb = *(const float4*)&w1[k];
    #pragma unroll
    for (int r=0;r<8;r++) {
      float4 av = *(const float4*)&arow[r][k];
      acc0[r] += av.x*wa.x + av.y*wa.y + av.z*wa.z + av.w*wa.w;
      acc1[r] += av.x*wb.x + av.y*wb.y + av.z*wb.z + av.w*wb.w;
    }
  }
  float bb0 = bvec[g0], bb1 = bvec[g0+1];
  #pragma unroll
  for (int r=0;r<8;r++) {
    size_t row = (size_t)blk*8 + r;
    xg[row*512 + g0]     = acc0[r] + bb0;
    xg[row*512 + g0 + 1] = acc1[r] + bb1;
  }
}

// ---------------- encoder LSTM scan: round-4 proven config (447 us, port-roofline) ----
__global__ __launch_bounds__(512, 2) void enc_scan_kernel(
    const float* __restrict__ xg, const float* __restrict__ Whh,
    float* __restrict__ hmean)
{
  __shared__ __align__(16) float h_s[128];
  __shared__ float act_s[512];
  const int b = blockIdx.x, tid = threadIdx.x;

  const f32x4* Wrow = (const f32x4*)(Whh + (size_t)tid*HH);
  f32x4 w[32];
  #pragma unroll
  for (int k=0;k<32;k++) w[k] = Wrow[k];
  #pragma unroll
  for (int k=0;k<32;k++) asm volatile("" : "+v"(w[k]));

  const float* xgrow = xg + (size_t)b*SS*512;
  float xv = xgrow[tid];
  if (tid < 128) h_s[tid] = 0.f;
  float cstate = 0.f, hsum = 0.f;
  __syncthreads();

  for (int t=0;t<SS;t++) {
    int tn = (t < SS-1) ? (t+1) : t;
    float nxv = xgrow[(size_t)tn*512 + tid];
    float a0=0.f,a1=0.f,a2=0.f,a3=0.f;
    #pragma unroll
    for (int k=0;k<32;k++) {
      f32x4 hv = *(const f32x4*)&h_s[k*4];
      a0 += w[k].x*hv.x; a1 += w[k].y*hv.y;
      a2 += w[k].z*hv.z; a3 += w[k].w*hv.w;
    }
    float s = (a0+a1)+(a2+a3) + xv;
    int gid = tid >> 7;
    float act = (gid==2) ? tanhf(s) : 1.0f/(1.0f+expf(-s));
    act_s[tid] = act;
    __syncthreads();
    if (tid < 128) {
      float i_ = act_s[tid], f_ = act_s[128+tid], g_ = act_s[256+tid], o_ = act_s[384+tid];
      cstate = f_*cstate + i_*g_;
      float hh = o_*tanhf(cstate);
      h_s[tid] = hh;
      hsum += hh;
    }
    xv = nxv;
    __syncthreads();
  }
  if (tid < 128) hmean[b*HH + tid] = hsum * (1.0f/512.0f);
}

// ---------------- FUSED decoder scan + output GEMM ----------------
// Blocks 0-7: decoder LSTM scan (round-4 body), publishing prog[b] every 64
// steps (threadfence + agent-scope release). Blocks 8+: 64x64 split-bf16 MFMA
// gemm tiles that acquire-spin until their A-chunk is published, hiding
// ~all of out_gemm under the scan's 447us. 84KB static LDS -> 1 block/CU, so
// gemm blocks never share a CU with (or slow) scan blocks. m-fast block order
// = earliest-timestep tiles dispatched first.
__global__ __launch_bounds__(512, 2) void dec_gemm_kernel(
    const float* __restrict__ xgdec, const float* __restrict__ Whh,
    __hip_bfloat16* __restrict__ ahi, __hip_bfloat16* __restrict__ alo,
    const __hip_bfloat16* __restrict__ Bhi, const __hip_bfloat16* __restrict__ Blo,
    const float* __restrict__ bo, float* __restrict__ out, int* __restrict__ prog)
{
  __shared__ __align__(16) char shraw[86016];   // 84KB: forces 1 block/CU
  const int bid = blockIdx.x, tid = threadIdx.x;

  if (bid < 8) {
    // ---------------- decoder scan role ----------------
    float* h_s   = (float*)shraw;               // 128 f32
    float* act_s = ((float*)shraw) + 128;       // 512 f32
    const int b = bid;

    const f32x4* Wrow = (const f32x4*)(Whh + (size_t)tid*HH);
    f32x4 w[32];
    #pragma unroll
    for (int k=0;k<32;k++) w[k] = Wrow[k];
    #pragma unroll
    for (int k=0;k<32;k++) asm volatile("" : "+v"(w[k]));

    float xv = xgdec[b*512 + tid];
    if (tid < 128) h_s[tid] = 0.f;
    float cstate = 0.f;
    __syncthreads();

    for (int t=0;t<SS;t++) {
      float a0=0.f,a1=0.f,a2=0.f,a3=0.f;
      #pragma unroll
      for (int k=0;k<32;k++) {
        f32x4 hv = *(const f32x4*)&h_s[k*4];
        a0 += w[k].x*hv.x; a1 += w[k].y*hv.y;
        a2 += w[k].z*hv.z; a3 += w[k].w*hv.w;
      }
      float s = (a0+a1)+(a2+a3) + xv;
      int gid = tid >> 7;
      float act = (gid==2) ? tanhf(s) : 1.0f/(1.0f+expf(-s));
      act_s[tid] = act;
      __syncthreads();
      if (tid < 128) {
        float i_ = act_s[tid], f_ = act_s[128+tid], g_ = act_s[256+tid], o_ = act_s[384+tid];
        cstate = f_*cstate + i_*g_;
        float hh = o_*tanhf(cstate);
        h_s[tid] = hh;
        size_t row = (size_t)b*SS + t;
        __hip_bfloat16 hi = __float2bfloat16(hh);
        float rem = hh - __bfloat162float(hi);
        ahi[row*HH + tid] = hi;
        alo[row*HH + tid] = __float2bfloat16(rem);
      }
      __syncthreads();
      if ((t & 63) == 63) {                     // publish completed 64-step chunk
        __threadfence();                        // writers drain to device scope
        __syncthreads();
        if (tid == 0)
          __hip_atomic_store(&prog[b], (t >> 6) + 1,
                             __ATOMIC_RELEASE, __HIP_MEMORY_SCOPE_AGENT);
      }
    }
  } else {
    // ---------------- gemm role: one 64x64 output tile ----------------
    short* smem = (short*)shraw;                // 4 planes x 16KB
    const int gbid = bid - 8;
    const int mblk = gbid & 63;                 // m-fast: low t first
    const int nblk = gbid >> 6;
    const int bneed = mblk >> 3;                // batch of this m-tile
    const int chunk = (mblk & 7) + 1;           // 64-step chunk required

    while (__hip_atomic_load(&prog[bneed], __ATOMIC_ACQUIRE,
                             __HIP_MEMORY_SCOPE_AGENT) < chunk)
      __builtin_amdgcn_s_sleep(16);

    const short* srcs[4] = {
      (const short*)ahi + (size_t)mblk*64*HH,
      (const short*)alo + (size_t)mblk*64*HH,
      (const short*)Bhi + (size_t)nblk*64*HH,
      (const short*)Blo + (size_t)nblk*64*HH };
    const int wuni  = (tid >> 6) * 1024;        // 8 waves x 1KB = 8KB per round
    const int lbyte = (tid & 63) * 16;
    #pragma unroll
    for (int p=0;p<4;p++) {
      #pragma unroll
      for (int it=0; it<2; it++) {
        int off  = it*8192 + wuni + lbyte;
        int row  = off >> 8;
        int soff = off ^ ((row & 15) << 4);     // inverse swizzle on SOURCE
        __builtin_amdgcn_global_load_lds(
          (const __attribute__((address_space(1))) void*)((const char*)srcs[p] + soff),
          (__attribute__((address_space(3))) void*)((char*)smem + p*16384 + it*8192 + wuni),
          16, 0, 0);
      }
    }
    __syncthreads();

    const int lane = tid & 63;
    const int wid  = tid >> 6;
    const int wm = wid >> 2, wn = wid & 3;      // 2x4 wave grid: 32x16 per wave
    const int l15 = lane & 15, l4 = lane >> 4;

    f32x4 acc[2] = {};
    #pragma unroll
    for (int s=0;s<4;s++) {
      s16x8 ah[2], al[2], bh, bl;
      #pragma unroll
      for (int q=0;q<2;q++) {
        int ra   = wm*32 + q*16 + l15;
        int offa = (ra*256 + s*64 + l4*16) ^ ((ra & 15) << 4);
        ah[q] = *(const s16x8*)((const char*)smem + offa);
        al[q] = *(const s16x8*)((const char*)smem + 16384 + offa);
      }
      int rb   = wn*16 + l15;
      int offb = (rb*256 + s*64 + l4*16) ^ ((rb & 15) << 4);
      bh = *(const s16x8*)((const char*)smem + 32768 + offb);
      bl = *(const s16x8*)((const char*)smem + 49152 + offb);
      #pragma unroll
      for (int q=0;q<2;q++) {
        acc[q] = __builtin_amdgcn_mfma_f32_16x16x32_bf16(bh, ah[q], acc[q], 0,0,0);
        acc[q] = __builtin_amdgcn_mfma_f32_16x16x32_bf16(bl, ah[q], acc[q], 0,0,0);
        acc[q] = __builtin_amdgcn_mfma_f32_16x16x32_bf16(bh, al[q], acc[q], 0,0,0);
      }
    }
    const int m0 = mblk*64 + wm*32;
    const int colb = nblk*64 + wn*16 + l4*4;    // 4 consecutive cols per lane
    f32x4 bv = *(const f32x4*)&bo[colb];
    #pragma unroll
    for (int q=0;q<2;q++) {
      int row = m0 + q*16 + l15;                // swapped C/D: l15 = M-row
      f32x4 o = acc[q] + bv;
      *(f32x4*)&out[(size_t)row*VV + colb] = o;
    }
  }
}

// ---------------- graph branch (collapsed to scalar edge passes) ----------------
__global__ __launch_bounds__(256) void edge_deg_kernel(const int* __restrict__ dst, float* __restrict__ deg) {
  int i = blockIdx.x*256 + threadIdx.x;
  if (i < NEDGE) atomicAdd(&deg[dst[i]], 1.0f);
}
__global__ __launch_bounds__(256) void node_dinv_kernel(const float* __restrict__ deg, float* __restrict__ dinv) {
  int n = blockIdx.x*256 + threadIdx.x;
  if (n < NNODE) dinv[n] = 1.0f / sqrtf(deg[n] + 1.0f);
}
__global__ __launch_bounds__(256) void edge_s1_kernel(const int* __restrict__ src, const int* __restrict__ dst,
    const float* __restrict__ dinv, float* __restrict__ s1) {
  int i = blockIdx.x*256 + threadIdx.x;
  if (i < NEDGE) atomicAdd(&s1[src[i]], dinv[dst[i]]);
}
__global__ __launch_bounds__(256) void node_c_kernel(const float* __restrict__ dinv, const float* __restrict__ s1,
    float* __restrict__ cc, float* __restrict__ csum) {
  __shared__ float red[256];
  int tid = threadIdx.x;
  int n = blockIdx.x*256 + tid;
  float v = 0.f;
  if (n < NNODE) { float d = dinv[n]; v = d*s1[n] + d*d; cc[n] = v; }
  red[tid] = v; __syncthreads();
  for (int sfl=128; sfl>0; sfl>>=1) { if (tid < sfl) red[tid] += red[tid+sfl]; __syncthreads(); }
  if (tid==0) atomicAdd(csum, red[0]);
}
__global__ __launch_bounds__(256) void edge_s2_kernel(const int* __restrict__ src, const int* __restrict__ dst,
    const float* __restrict__ dinv, const float* __restrict__ cc, float* __restrict__ s2) {
  int i = blockIdx.x*256 + threadIdx.x;
  if (i < NEDGE) { int d = dst[i]; atomicAdd(&s2[src[i]], cc[d]*dinv[d]); }
}
__global__ __launch_bounds__(256) void node_e_kernel(const float* __restrict__ dinv, const float* __restrict__ s2,
    const float* __restrict__ cc, float* __restrict__ ee) {
  int n = blockIdx.x*256 + threadIdx.x;
  if (n < NNODE) { float d = dinv[n]; ee[n] = d*s2[n] + cc[n]*d*d; }
}
__global__ __launch_bounds__(256) void gvec_kernel(const int* __restrict__ nids, const float* __restrict__ emb,
    const float* __restrict__ ee, float* __restrict__ gvec) {
  __shared__ float red[256];
  int tid = threadIdx.x;
  int j = tid & 127, sub = tid >> 7;
  float acc = 0.f;
  for (int n = blockIdx.x*2 + sub; n < NNODE; n += gridDim.x*2) {
    acc += ee[n] * emb[(size_t)nids[n]*HH + j];
  }
  red[tid] = acc; __syncthreads();
  if (tid < 128) atomicAdd(&gvec[j], red[tid] + red[tid+128]);
}
__global__ void graph_final_kernel(const float* __restrict__ gvec, const float* __restrict__ csum,
    const float* __restrict__ W1, const float* __restrict__ b1,
    const float* __restrict__ W2, const float* __restrict__ b2, float* __restrict__ mvec) {
  __shared__ float gs[128], v1[128];
  int j = threadIdx.x;
  gs[j] = gvec[j];
  __syncthreads();
  float a = 0.f;
  for (int k=0;k<128;k++) a += gs[k]*W1[j*128+k];
  v1[j] = a + csum[0]*b1[j];
  __syncthreads();
  float a2 = 0.f;
  for (int k=0;k<128;k++) a2 += v1[k]*W2[j*128+k];
  mvec[j] = a2 * (1.0f/(float)NNODE) + b2[j];
}

// ---------------- fusion ----------------
__global__ __launch_bounds__(512) void fusion_kernel(const float* __restrict__ hmean, const float* __restrict__ mvec,
    const float* __restrict__ Wf, const float* __restrict__ bfv,
    const float* __restrict__ Wihd, const float* __restrict__ bd, float* __restrict__ xgdec)
{
  __shared__ float comb[256];
  __shared__ float fus[128];
  int b = blockIdx.x, tid = threadIdx.x;
  if (tid < 128) comb[tid] = hmean[b*128 + tid];
  else if (tid < 256) comb[tid] = mvec[tid - 128];
  __syncthreads();
  if (tid < 128) {
    float a = 0.f;
    for (int k=0;k<256;k++) a += comb[k]*Wf[tid*256+k];
    fus[tid] = a + bfv[tid];
  }
  __syncthreads();
  float a = 0.f;
  for (int k=0;k<128;k++) a += fus[k]*Wihd[tid*128+k];
  xgdec[b*512 + tid] = a + bd[tid];
}

// ---------------- split fp32 -> (bf16 hi, bf16 lo) ----------------
__global__ __launch_bounds__(256) void split_bf16_kernel(const float* __restrict__ x,
    __hip_bfloat16* __restrict__ hi, __hip_bfloat16* __restrict__ lo, int n4) {
  int i = blockIdx.x*256 + threadIdx.x;
  if (i >= n4) return;
  float4 v = *(const float4*)&x[i*4];
  float vv[4] = {v.x, v.y, v.z, v.w};
  #pragma unroll
  for (int k=0;k<4;k++) {
    __hip_bfloat16 h = __float2bfloat16(vv[k]);
    hi[i*4+k] = h;
    lo[i*4+k] = __float2bfloat16(vv[k] - __bfloat162float(h));
  }
}

// ---------------- launch ----------------
extern "C" void kernel_launch(void* const* d_in, const int* in_sizes, int n_in,
                              void* d_out, int out_size, void* d_ws, size_t ws_size,
                              hipStream_t stream)
{
  (void)in_sizes; (void)n_in; (void)out_size; (void)ws_size;
  const int*   jin   = (const int*)d_in[0];
  const int*   nids  = (const int*)d_in[1];
  const int*   esrc  = (const int*)d_in[2];
  const int*   edst  = esrc + NEDGE;
  const float* emb   = (const float*)d_in[3];
  const float* WihE  = (const float*)d_in[4];
  const float* WhhE  = (const float*)d_in[5];
  const float* bE    = (const float*)d_in[6];
  const float* W1    = (const float*)d_in[7];
  const float* b1    = (const float*)d_in[8];
  const float* W2    = (const float*)d_in[9];
  const float* b2    = (const float*)d_in[10];
  const float* Wf    = (const float*)d_in[11];
  const float* bfv   = (const float*)d_in[12];
  const float* WihD  = (const float*)d_in[13];
  const float* WhhD  = (const float*)d_in[14];
  const float* bD    = (const float*)d_in[15];
  const float* Wo    = (const float*)d_in[16];
  const float* bo    = (const float*)d_in[17];
  float* out = (float*)d_out;

  char* ws = (char*)d_ws;
  size_t off = 0;
  auto alloc = [&](size_t bytes) { size_t o = off; off = (off + bytes + 255) & ~(size_t)255; return o; };

  int*   prog = (int*)(ws + alloc(BB*4));          // decoder progress counters
  float* deg  = (float*)(ws + alloc(NNODE*4));
  float* s1   = (float*)(ws + alloc(NNODE*4));
  float* s2   = (float*)(ws + alloc(NNODE*4));
  float* gvec = (float*)(ws + alloc(128*4));
  float* csum = (float*)(ws + alloc(4));
  size_t zero_bytes = off;                         // [prog,deg,s1,s2,gvec,csum]
  float* dinv = (float*)(ws + alloc(NNODE*4));
  float* cc   = (float*)(ws + alloc(NNODE*4));
  float* ee   = (float*)(ws + alloc(NNODE*4));
  float* mvec = (float*)(ws + alloc(128*4));
  float* hmean= (float*)(ws + alloc(BB*HH*4));
  float* xgdec= (float*)(ws + alloc(BB*512*4));
  float* xgenc= (float*)(ws + alloc((size_t)BB*SS*512*4));
  __hip_bfloat16* Ahi = (__hip_bfloat16*)(ws + alloc((size_t)BB*SS*HH*2));
  __hip_bfloat16* Alo = (__hip_bfloat16*)(ws + alloc((size_t)BB*SS*HH*2));
  __hip_bfloat16* Bhi = (__hip_bfloat16*)(ws + alloc((size_t)VV*HH*2));
  __hip_bfloat16* Blo = (__hip_bfloat16*)(ws + alloc((size_t)VV*HH*2));

  hipMemsetAsync(ws, 0, zero_bytes, stream);

  // independent prep first: B-operand split (needed by fused kernel)
  split_bf16_kernel<<<dim3((VV*HH/4+255)/256), dim3(256), 0, stream>>>(Wo, Bhi, Blo, VV*HH/4);

  // sequence branch
  xg_enc_kernel<<<dim3((BB*SS)/8), dim3(256), 0, stream>>>(jin, emb, WihE, bE, xgenc);
  enc_scan_kernel<<<dim3(BB), dim3(512), 0, stream>>>(xgenc, WhhE, hmean);

  // graph branch (collapsed)
  edge_deg_kernel<<<dim3((NEDGE+255)/256), dim3(256), 0, stream>>>(edst, deg);
  node_dinv_kernel<<<dim3((NNODE+255)/256), dim3(256), 0, stream>>>(deg, dinv);
  edge_s1_kernel<<<dim3((NEDGE+255)/256), dim3(256), 0, stream>>>(esrc, edst, dinv, s1);
  node_c_kernel<<<dim3((NNODE+255)/256), dim3(256), 0, stream>>>(dinv, s1, cc, csum);
  edge_s2_kernel<<<dim3((NEDGE+255)/256), dim3(256), 0, stream>>>(esrc, edst, dinv, cc, s2);
  node_e_kernel<<<dim3((NNODE+255)/256), dim3(256), 0, stream>>>(dinv, s2, cc, ee);
  gvec_kernel<<<dim3(256), dim3(256), 0, stream>>>(nids, emb, ee, gvec);
  graph_final_kernel<<<dim3(1), dim3(128), 0, stream>>>(gvec, csum, W1, b1, W2, b2, mvec);

  // fusion, then fused decoder-scan + output-GEMM (gemm hidden under the scan)
  fusion_kernel<<<dim3(BB), dim3(512), 0, stream>>>(hmean, mvec, Wf, bfv, WihD, bD, xgdec);
  dec_gemm_kernel<<<dim3(8 + 64*(VV/64)), dim3(512), 0, stream>>>(
      xgdec, WhhD, Ahi, Alo, Bhi, Blo, bo, out, prog);
}

// Round 13
// 1284.122 us; speedup vs baseline: 3.3740x; 2.4938x over previous
//
#include <hip/hip_runtime.h>
#include <hip/hip_bf16.h>
#include <stdint.h>

#define VV 32000
#define HH 128
#define BB 8
#define SS 512
#define NNODE 50000
#define NEDGE 600000

typedef __attribute__((ext_vector_type(8))) short s16x8;
typedef __attribute__((ext_vector_type(4))) float f32x4;

// ---------------- embedding gather + encoder input-gate GEMM ----------------
__global__ __launch_bounds__(256) void xg_enc_kernel(
    const int* __restrict__ jin, const float* __restrict__ emb,
    const float* __restrict__ Wih, const float* __restrict__ bvec,
    float* __restrict__ xg)
{
  __shared__ __align__(16) float arow[8][128];
  const int tid = threadIdx.x, blk = blockIdx.x;
  {
    int r = tid >> 5, c = (tid & 31) << 2;
    int tok = jin[blk*8 + r];
    *(float4*)&arow[r][c] = *(const float4*)&emb[(size_t)tok*HH + c];
  }
  __syncthreads();
  const int g0 = tid * 2;
  const float* w0 = Wih + (size_t)g0*HH;
  const float* w1 = w0 + HH;
  float acc0[8], acc1[8];
  #pragma unroll
  for (int r=0;r<8;r++){ acc0[r]=0.f; acc1[r]=0.f; }
  for (int k=0;k<HH;k+=4) {
    float4 wa = *(const float4*)&w0[k];
    float4 wb = *(const float4*)&w1[k];
    #pragma unroll
    for (int r=0;r<8;r++) {
      float4 av = *(const float4*)&arow[r][k];
      acc0[r] += av.x*wa.x + av.y*wa.y + av.z*wa.z + av.w*wa.w;
      acc1[r] += av.x*wb.x + av.y*wb.y + av.z*wb.z + av.w*wb.w;
    }
  }
  float bb0 = bvec[g0], bb1 = bvec[g0+1];
  #pragma unroll
  for (int r=0;r<8;r++) {
    size_t row = (size_t)blk*8 + r;
    xg[row*512 + g0]     = acc0[r] + bb0;
    xg[row*512 + g0 + 1] = acc1[r] + bb1;
  }
}

// ---------------- encoder LSTM scan: round-4 proven config (447 us, port-roofline) ----
__global__ __launch_bounds__(512, 2) void enc_scan_kernel(
    const float* __restrict__ xg, const float* __restrict__ Whh,
    float* __restrict__ hmean)
{
  __shared__ __align__(16) float h_s[128];
  __shared__ float act_s[512];
  const int b = blockIdx.x, tid = threadIdx.x;

  const f32x4* Wrow = (const f32x4*)(Whh + (size_t)tid*HH);
  f32x4 w[32];
  #pragma unroll
  for (int k=0;k<32;k++) w[k] = Wrow[k];
  #pragma unroll
  for (int k=0;k<32;k++) asm volatile("" : "+v"(w[k]));

  const float* xgrow = xg + (size_t)b*SS*512;
  float xv = xgrow[tid];
  if (tid < 128) h_s[tid] = 0.f;
  float cstate = 0.f, hsum = 0.f;
  __syncthreads();

  for (int t=0;t<SS;t++) {
    int tn = (t < SS-1) ? (t+1) : t;
    float nxv = xgrow[(size_t)tn*512 + tid];
    float a0=0.f,a1=0.f,a2=0.f,a3=0.f;
    #pragma unroll
    for (int k=0;k<32;k++) {
      f32x4 hv = *(const f32x4*)&h_s[k*4];
      a0 += w[k].x*hv.x; a1 += w[k].y*hv.y;
      a2 += w[k].z*hv.z; a3 += w[k].w*hv.w;
    }
    float s = (a0+a1)+(a2+a3) + xv;
    int gid = tid >> 7;
    float act = (gid==2) ? tanhf(s) : 1.0f/(1.0f+expf(-s));
    act_s[tid] = act;
    __syncthreads();
    if (tid < 128) {
      float i_ = act_s[tid], f_ = act_s[128+tid], g_ = act_s[256+tid], o_ = act_s[384+tid];
      cstate = f_*cstate + i_*g_;
      float hh = o_*tanhf(cstate);
      h_s[tid] = hh;
      hsum += hh;
    }
    xv = nxv;
    __syncthreads();
  }
  if (tid < 128) hmean[b*HH + tid] = hsum * (1.0f/512.0f);
}

// ---------------- FUSED decoder scan + output GEMM (round-12 repaired) ----------
// Blocks 0-7: decoder scan, publishing prog[b*32] (one 128B line per batch)
// every 128 steps. Blocks 8+: 128x256 output tiles in CHUNK-MAJOR order; only
// tid==0 polls (s_sleep(64)), then __syncthreads. B (hi+lo) staged in 128KB
// LDS (1 block/CU -> never co-resident with scan); A fragments read directly
// from global (2MB, L2-hot).
__global__ __launch_bounds__(512) void dec_gemm_kernel(
    const float* __restrict__ xgdec, const float* __restrict__ Whh,
    __hip_bfloat16* __restrict__ ahi, __hip_bfloat16* __restrict__ alo,
    const __hip_bfloat16* __restrict__ Bhi, const __hip_bfloat16* __restrict__ Blo,
    const float* __restrict__ bo, float* __restrict__ out, int* __restrict__ prog)
{
  __shared__ __align__(16) char shraw[131072];   // 128KB -> 1 block/CU
  const int bid = blockIdx.x, tid = threadIdx.x;

  if (bid < 8) {
    // ---------------- decoder scan role (round-4 body) ----------------
    float* h_s   = (float*)shraw;
    float* act_s = ((float*)shraw) + 128;
    const int b = bid;

    const f32x4* Wrow = (const f32x4*)(Whh + (size_t)tid*HH);
    f32x4 w[32];
    #pragma unroll
    for (int k=0;k<32;k++) w[k] = Wrow[k];
    #pragma unroll
    for (int k=0;k<32;k++) asm volatile("" : "+v"(w[k]));

    float xv = xgdec[b*512 + tid];
    if (tid < 128) h_s[tid] = 0.f;
    float cstate = 0.f;
    __syncthreads();

    for (int t=0;t<SS;t++) {
      float a0=0.f,a1=0.f,a2=0.f,a3=0.f;
      #pragma unroll
      for (int k=0;k<32;k++) {
        f32x4 hv = *(const f32x4*)&h_s[k*4];
        a0 += w[k].x*hv.x; a1 += w[k].y*hv.y;
        a2 += w[k].z*hv.z; a3 += w[k].w*hv.w;
      }
      float s = (a0+a1)+(a2+a3) + xv;
      int gid = tid >> 7;
      float act = (gid==2) ? tanhf(s) : 1.0f/(1.0f+expf(-s));
      act_s[tid] = act;
      __syncthreads();
      if (tid < 128) {
        float i_ = act_s[tid], f_ = act_s[128+tid], g_ = act_s[256+tid], o_ = act_s[384+tid];
        cstate = f_*cstate + i_*g_;
        float hh = o_*tanhf(cstate);
        h_s[tid] = hh;
        size_t row = (size_t)b*SS + t;
        __hip_bfloat16 hi = __float2bfloat16(hh);
        float rem = hh - __bfloat162float(hi);
        ahi[row*HH + tid] = hi;
        alo[row*HH + tid] = __float2bfloat16(rem);
      }
      __syncthreads();
      if ((t & 127) == 127) {                   // publish completed 128-step chunk
        __threadfence();
        __syncthreads();
        if (tid == 0)
          __hip_atomic_store(&prog[b*32], (t >> 7) + 1,
                             __ATOMIC_RELEASE, __HIP_MEMORY_SCOPE_AGENT);
      }
    }
  } else {
    // ---------------- gemm role: one 128x256 output tile ----------------
    short* smem = (short*)shraw;                // hi plane @0, lo plane @64KB
    const int gbid = bid - 8;
    const int c    = gbid / 1000;               // chunk-major: c = 0..3
    const int r    = gbid % 1000;
    const int b    = r / 125;                   // batch
    const int nblk = r % 125;                   // 256-col tile
    const int mtile = b*4 + c;                  // rows mtile*128..+128

    if (tid == 0) {                             // single-lane, slow poll
      while (__hip_atomic_load(&prog[b*32], __ATOMIC_ACQUIRE,
                               __HIP_MEMORY_SCOPE_AGENT) <= c)
        __builtin_amdgcn_s_sleep(64);
    }
    __syncthreads();

    // stage B tile (256 cols x 128 k, hi+lo) into LDS, inverse-swizzled source
    const short* bsrc[2] = {
      (const short*)Bhi + (size_t)nblk*256*HH,
      (const short*)Blo + (size_t)nblk*256*HH };
    #pragma unroll
    for (int p=0;p<2;p++) {
      #pragma unroll
      for (int it=0; it<8; it++) {
        int off  = it*8192 + tid*16;            // linear byte offset in plane
        int row  = off >> 8;                    // 256B per B-row (col)
        int soff = off ^ ((row & 15) << 4);
        __builtin_amdgcn_global_load_lds(
          (const __attribute__((address_space(1))) void*)((const char*)bsrc[p] + soff),
          (__attribute__((address_space(3))) void*)((char*)smem + p*65536 + off),
          16, 0, 0);
      }
    }
    __syncthreads();

    const int lane = tid & 63;
    const int wid  = tid >> 6;
    const int wm = wid >> 2, wn = wid & 3;      // 2m x 4n waves: 64x64 each
    const int l15 = lane & 15, l4 = lane >> 4;
    const int mbase = mtile*128 + wm*64;
    const short* Ah = (const short*)ahi;
    const short* Al = (const short*)alo;

    f32x4 acc[4][4] = {};
    #pragma unroll
    for (int s=0;s<4;s++) {
      s16x8 bh[4], bl[4], ah[4], al[4];
      #pragma unroll
      for (int qn=0;qn<4;qn++) {
        int rb   = wn*64 + qn*16 + l15;
        int offb = (rb*256 + s*64 + l4*16) ^ ((rb & 15) << 4);
        bh[qn] = *(const s16x8*)((const char*)smem + offb);
        bl[qn] = *(const s16x8*)((const char*)smem + 65536 + offb);
      }
      #pragma unroll
      for (int qm=0;qm<4;qm++) {
        int arow = mbase + qm*16 + l15;
        size_t aoff = (size_t)arow*HH + s*32 + l4*8;
        ah[qm] = *(const s16x8*)(Ah + aoff);    // A direct from global (L2-hot)
        al[qm] = *(const s16x8*)(Al + aoff);
      }
      #pragma unroll
      for (int qm=0;qm<4;qm++) {
        #pragma unroll
        for (int qn=0;qn<4;qn++) {
          acc[qm][qn] = __builtin_amdgcn_mfma_f32_16x16x32_bf16(bh[qn], ah[qm], acc[qm][qn], 0,0,0);
          acc[qm][qn] = __builtin_amdgcn_mfma_f32_16x16x32_bf16(bl[qn], ah[qm], acc[qm][qn], 0,0,0);
          acc[qm][qn] = __builtin_amdgcn_mfma_f32_16x16x32_bf16(bh[qn], al[qm], acc[qm][qn], 0,0,0);
        }
      }
    }
    #pragma unroll
    for (int qm=0;qm<4;qm++) {
      int row = mbase + qm*16 + l15;            // swapped C/D: l15 = M-row
      #pragma unroll
      for (int qn=0;qn<4;qn++) {
        int colb = nblk*256 + wn*64 + qn*16 + l4*4;
        f32x4 bv = *(const f32x4*)&bo[colb];
        f32x4 o = acc[qm][qn] + bv;
        *(f32x4*)&out[(size_t)row*VV + colb] = o;
      }
    }
  }
}

// ---------------- graph branch (collapsed to scalar edge passes) ----------------
__global__ __launch_bounds__(256) void edge_deg_kernel(const int* __restrict__ dst, float* __restrict__ deg) {
  int i = blockIdx.x*256 + threadIdx.x;
  if (i < NEDGE) atomicAdd(&deg[dst[i]], 1.0f);
}
__global__ __launch_bounds__(256) void node_dinv_kernel(const float* __restrict__ deg, float* __restrict__ dinv) {
  int n = blockIdx.x*256 + threadIdx.x;
  if (n < NNODE) dinv[n] = 1.0f / sqrtf(deg[n] + 1.0f);
}
__global__ __launch_bounds__(256) void edge_s1_kernel(const int* __restrict__ src, const int* __restrict__ dst,
    const float* __restrict__ dinv, float* __restrict__ s1) {
  int i = blockIdx.x*256 + threadIdx.x;
  if (i < NEDGE) atomicAdd(&s1[src[i]], dinv[dst[i]]);
}
__global__ __launch_bounds__(256) void node_c_kernel(const float* __restrict__ dinv, const float* __restrict__ s1,
    float* __restrict__ cc, float* __restrict__ csum) {
  __shared__ float red[256];
  int tid = threadIdx.x;
  int n = blockIdx.x*256 + tid;
  float v = 0.f;
  if (n < NNODE) { float d = dinv[n]; v = d*s1[n] + d*d; cc[n] = v; }
  red[tid] = v; __syncthreads();
  for (int sfl=128; sfl>0; sfl>>=1) { if (tid < sfl) red[tid] += red[tid+sfl]; __syncthreads(); }
  if (tid==0) atomicAdd(csum, red[0]);
}
__global__ __launch_bounds__(256) void edge_s2_kernel(const int* __restrict__ src, const int* __restrict__ dst,
    const float* __restrict__ dinv, const float* __restrict__ cc, float* __restrict__ s2) {
  int i = blockIdx.x*256 + threadIdx.x;
  if (i < NEDGE) { int d = dst[i]; atomicAdd(&s2[src[i]], cc[d]*dinv[d]); }
}
__global__ __launch_bounds__(256) void node_e_kernel(const float* __restrict__ dinv, const float* __restrict__ s2,
    const float* __restrict__ cc, float* __restrict__ ee) {
  int n = blockIdx.x*256 + threadIdx.x;
  if (n < NNODE) { float d = dinv[n]; ee[n] = d*s2[n] + cc[n]*d*d; }
}
__global__ __launch_bounds__(256) void gvec_kernel(const int* __restrict__ nids, const float* __restrict__ emb,
    const float* __restrict__ ee, float* __restrict__ gvec) {
  __shared__ float red[256];
  int tid = threadIdx.x;
  int j = tid & 127, sub = tid >> 7;
  float acc = 0.f;
  for (int n = blockIdx.x*2 + sub; n < NNODE; n += gridDim.x*2) {
    acc += ee[n] * emb[(size_t)nids[n]*HH + j];
  }
  red[tid] = acc; __syncthreads();
  if (tid < 128) atomicAdd(&gvec[j], red[tid] + red[tid+128]);
}
__global__ void graph_final_kernel(const float* __restrict__ gvec, const float* __restrict__ csum,
    const float* __restrict__ W1, const float* __restrict__ b1,
    const float* __restrict__ W2, const float* __restrict__ b2, float* __restrict__ mvec) {
  __shared__ float gs[128], v1[128];
  int j = threadIdx.x;
  gs[j] = gvec[j];
  __syncthreads();
  float a = 0.f;
  for (int k=0;k<128;k++) a += gs[k]*W1[j*128+k];
  v1[j] = a + csum[0]*b1[j];
  __syncthreads();
  float a2 = 0.f;
  for (int k=0;k<128;k++) a2 += v1[k]*W2[j*128+k];
  mvec[j] = a2 * (1.0f/(float)NNODE) + b2[j];
}

// ---------------- fusion ----------------
__global__ __launch_bounds__(512) void fusion_kernel(const float* __restrict__ hmean, const float* __restrict__ mvec,
    const float* __restrict__ Wf, const float* __restrict__ bfv,
    const float* __restrict__ Wihd, const float* __restrict__ bd, float* __restrict__ xgdec)
{
  __shared__ float comb[256];
  __shared__ float fus[128];
  int b = blockIdx.x, tid = threadIdx.x;
  if (tid < 128) comb[tid] = hmean[b*128 + tid];
  else if (tid < 256) comb[tid] = mvec[tid - 128];
  __syncthreads();
  if (tid < 128) {
    float a = 0.f;
    for (int k=0;k<256;k++) a += comb[k]*Wf[tid*256+k];
    fus[tid] = a + bfv[tid];
  }
  __syncthreads();
  float a = 0.f;
  for (int k=0;k<128;k++) a += fus[k]*Wihd[tid*128+k];
  xgdec[b*512 + tid] = a + bd[tid];
}

// ---------------- split fp32 -> (bf16 hi, bf16 lo) ----------------
__global__ __launch_bounds__(256) void split_bf16_kernel(const float* __restrict__ x,
    __hip_bfloat16* __restrict__ hi, __hip_bfloat16* __restrict__ lo, int n4) {
  int i = blockIdx.x*256 + threadIdx.x;
  if (i >= n4) return;
  float4 v = *(const float4*)&x[i*4];
  float vv[4] = {v.x, v.y, v.z, v.w};
  #pragma unroll
  for (int k=0;k<4;k++) {
    __hip_bfloat16 h = __float2bfloat16(vv[k]);
    hi[i*4+k] = h;
    lo[i*4+k] = __float2bfloat16(vv[k] - __bfloat162float(h));
  }
}

// ---------------- launch ----------------
extern "C" void kernel_launch(void* const* d_in, const int* in_sizes, int n_in,
                              void* d_out, int out_size, void* d_ws, size_t ws_size,
                              hipStream_t stream)
{
  (void)in_sizes; (void)n_in; (void)out_size; (void)ws_size;
  const int*   jin   = (const int*)d_in[0];
  const int*   nids  = (const int*)d_in[1];
  const int*   esrc  = (const int*)d_in[2];
  const int*   edst  = esrc + NEDGE;
  const float* emb   = (const float*)d_in[3];
  const float* WihE  = (const float*)d_in[4];
  const float* WhhE  = (const float*)d_in[5];
  const float* bE    = (const float*)d_in[6];
  const float* W1    = (const float*)d_in[7];
  const float* b1    = (const float*)d_in[8];
  const float* W2    = (const float*)d_in[9];
  const float* b2    = (const float*)d_in[10];
  const float* Wf    = (const float*)d_in[11];
  const float* bfv   = (const float*)d_in[12];
  const float* WihD  = (const float*)d_in[13];
  const float* WhhD  = (const float*)d_in[14];
  const float* bD    = (const float*)d_in[15];
  const float* Wo    = (const float*)d_in[16];
  const float* bo    = (const float*)d_in[17];
  float* out = (float*)d_out;

  char* ws = (char*)d_ws;
  size_t off = 0;
  auto alloc = [&](size_t bytes) { size_t o = off; off = (off + bytes + 255) & ~(size_t)255; return o; };

  int*   prog = (int*)(ws + alloc(BB*32*4));       // 1 cache line per batch
  float* deg  = (float*)(ws + alloc(NNODE*4));
  float* s1   = (float*)(ws + alloc(NNODE*4));
  float* s2   = (float*)(ws + alloc(NNODE*4));
  float* gvec = (float*)(ws + alloc(128*4));
  float* csum = (float*)(ws + alloc(4));
  size_t zero_bytes = off;                         // [prog,deg,s1,s2,gvec,csum]
  float* dinv = (float*)(ws + alloc(NNODE*4));
  float* cc   = (float*)(ws + alloc(NNODE*4));
  float* ee   = (float*)(ws + alloc(NNODE*4));
  float* mvec = (float*)(ws + alloc(128*4));
  float* hmean= (float*)(ws + alloc(BB*HH*4));
  float* xgdec= (float*)(ws + alloc(BB*512*4));
  float* xgenc= (float*)(ws + alloc((size_t)BB*SS*512*4));
  __hip_bfloat16* Ahi = (__hip_bfloat16*)(ws + alloc((size_t)BB*SS*HH*2));
  __hip_bfloat16* Alo = (__hip_bfloat16*)(ws + alloc((size_t)BB*SS*HH*2));
  __hip_bfloat16* Bhi = (__hip_bfloat16*)(ws + alloc((size_t)VV*HH*2));
  __hip_bfloat16* Blo = (__hip_bfloat16*)(ws + alloc((size_t)VV*HH*2));

  hipMemsetAsync(ws, 0, zero_bytes, stream);

  // independent prep: B-operand split (needed by fused kernel)
  split_bf16_kernel<<<dim3((VV*HH/4+255)/256), dim3(256), 0, stream>>>(Wo, Bhi, Blo, VV*HH/4);

  // sequence branch
  xg_enc_kernel<<<dim3((BB*SS)/8), dim3(256), 0, stream>>>(jin, emb, WihE, bE, xgenc);
  enc_scan_kernel<<<dim3(BB), dim3(512), 0, stream>>>(xgenc, WhhE, hmean);

  // graph branch (collapsed)
  edge_deg_kernel<<<dim3((NEDGE+255)/256), dim3(256), 0, stream>>>(edst, deg);
  node_dinv_kernel<<<dim3((NNODE+255)/256), dim3(256), 0, stream>>>(deg, dinv);
  edge_s1_kernel<<<dim3((NEDGE+255)/256), dim3(256), 0, stream>>>(esrc, edst, dinv, s1);
  node_c_kernel<<<dim3((NNODE+255)/256), dim3(256), 0, stream>>>(dinv, s1, cc, csum);
  edge_s2_kernel<<<dim3((NEDGE+255)/256), dim3(256), 0, stream>>>(esrc, edst, dinv, cc, s2);
  node_e_kernel<<<dim3((NNODE+255)/256), dim3(256), 0, stream>>>(dinv, s2, cc, ee);
  gvec_kernel<<<dim3(256), dim3(256), 0, stream>>>(nids, emb, ee, gvec);
  graph_final_kernel<<<dim3(1), dim3(128), 0, stream>>>(gvec, csum, W1, b1, W2, b2, mvec);

  // fusion, then fused decoder-scan + output-GEMM (gemm hidden under the scan)
  fusion_kernel<<<dim3(BB), dim3(512), 0, stream>>>(hmean, mvec, Wf, bfv, WihD, bD, xgdec);
  dec_gemm_kernel<<<dim3(8 + 4000), dim3(512), 0, stream>>>(
      xgdec, WhhD, Ahi, Alo, Bhi, Blo, bo, out, prog);
}

// Round 14
// 1251.875 us; speedup vs baseline: 3.4610x; 1.0258x over previous
//
#include <hip/hip_runtime.h>
#include <hip/hip_bf16.h>
#include <stdint.h>

#define VV 32000
#define HH 128
#define BB 8
#define SS 512
#define NNODE 50000
#define NEDGE 600000
#define NWORK 240          // worker blocks in front kernel (248 total <= 256 CUs)

typedef __attribute__((ext_vector_type(8))) short s16x8;
typedef __attribute__((ext_vector_type(4))) float f32x4;

__device__ __forceinline__ void workers_barrier(int* bar, int tid) {
  __syncthreads();
  if (tid == 0) {
    int g = __hip_atomic_load(&bar[32], __ATOMIC_ACQUIRE, __HIP_MEMORY_SCOPE_AGENT);
    int old = __hip_atomic_fetch_add(&bar[0], 1, __ATOMIC_ACQ_REL, __HIP_MEMORY_SCOPE_AGENT);
    if (old == NWORK-1) {
      __hip_atomic_store(&bar[0], 0, __ATOMIC_RELAXED, __HIP_MEMORY_SCOPE_AGENT);
      __hip_atomic_store(&bar[32], g+1, __ATOMIC_RELEASE, __HIP_MEMORY_SCOPE_AGENT);
    } else {
      while (__hip_atomic_load(&bar[32], __ATOMIC_ACQUIRE, __HIP_MEMORY_SCOPE_AGENT) == g)
        __builtin_amdgcn_s_sleep(32);
    }
  }
  __syncthreads();
}

// ---------------- FRONT: enc scan (blocks 0-7) + workers (xg, split, graph) ----
__global__ __launch_bounds__(512) void front_kernel(
    const int* __restrict__ jin, const float* __restrict__ emb,
    const float* __restrict__ WihE, const float* __restrict__ bE,
    float* xg, const float* __restrict__ WhhE, float* __restrict__ hmean,
    const float* __restrict__ Wo, __hip_bfloat16* __restrict__ Bhi, __hip_bfloat16* __restrict__ Blo,
    const int* __restrict__ esrc, const int* __restrict__ edst, const int* __restrict__ nids,
    float* __restrict__ deg, float* __restrict__ dinv, float* __restrict__ s1,
    float* __restrict__ s2, float* __restrict__ cc, float* __restrict__ ee,
    float* __restrict__ csum, float* __restrict__ gvec,
    const float* __restrict__ W1, const float* __restrict__ b1,
    const float* __restrict__ W2, const float* __restrict__ b2, float* __restrict__ mvec,
    int* ucnt, int* bar)
{
  __shared__ __align__(16) char shraw[131072];   // 128KB -> 1 block/CU (isolation)
  const int bid = blockIdx.x, tid = threadIdx.x;

  if (bid < 8) {
    // ---------------- encoder scan role (round-4 body + xg chunk gating) -------
    float* h_s   = (float*)shraw;
    float* act_s = ((float*)shraw) + 128;
    const int b = bid;

    const f32x4* Wrow = (const f32x4*)(WhhE + (size_t)tid*HH);
    f32x4 w[32];
    #pragma unroll
    for (int k=0;k<32;k++) w[k] = Wrow[k];
    #pragma unroll
    for (int k=0;k<32;k++) asm volatile("" : "+v"(w[k]));

    const float* xgrow = xg + (size_t)b*SS*512;
    // wait for chunk 0 of this batch
    if (tid == 0) {
      while (__hip_atomic_load(&ucnt[(b*8+0)*32], __ATOMIC_ACQUIRE, __HIP_MEMORY_SCOPE_AGENT) < 8)
        __builtin_amdgcn_s_sleep(16);
    }
    __syncthreads();
    float xv = xgrow[tid];
    if (tid < 128) h_s[tid] = 0.f;
    float cstate = 0.f, hsum = 0.f;
    __syncthreads();

    for (int t=0;t<SS;t++) {
      if ((t & 63) == 0) {                       // gate next chunk (covers prefetch)
        int cn = (t >> 6) + 1; if (cn > 7) cn = 7;
        if (tid == 0) {
          while (__hip_atomic_load(&ucnt[(b*8+cn)*32], __ATOMIC_ACQUIRE, __HIP_MEMORY_SCOPE_AGENT) < 8)
            __builtin_amdgcn_s_sleep(16);
        }
        __syncthreads();
      }
      int tn = (t < SS-1) ? (t+1) : t;
      float nxv = xgrow[(size_t)tn*512 + tid];
      float a0=0.f,a1=0.f,a2=0.f,a3=0.f;
      #pragma unroll
      for (int k=0;k<32;k++) {
        f32x4 hv = *(const f32x4*)&h_s[k*4];
        a0 += w[k].x*hv.x; a1 += w[k].y*hv.y;
        a2 += w[k].z*hv.z; a3 += w[k].w*hv.w;
      }
      float s = (a0+a1)+(a2+a3) + xv;
      int gid = tid >> 7;
      float act = (gid==2) ? tanhf(s) : 1.0f/(1.0f+expf(-s));
      act_s[tid] = act;
      __syncthreads();
      if (tid < 128) {
        float i_ = act_s[tid], f_ = act_s[128+tid], g_ = act_s[256+tid], o_ = act_s[384+tid];
        cstate = f_*cstate + i_*g_;
        float hh = o_*tanhf(cstate);
        h_s[tid] = hh;
        hsum += hh;
      }
      xv = nxv;
      __syncthreads();
    }
    if (tid < 128) hmean[b*HH + tid] = hsum * (1.0f/512.0f);
  } else {
    // ---------------- worker role ---------------------------------------------
    const int wbid = bid - 8;
    float (*arow)[128] = (float(*)[128])shraw;   // 8x128 staging
    float* red = (float*)(shraw + 8*128*4);      // 512 reduce scratch

    // P0a: xg production, chunk-major units of 8 rows
    for (int u = wbid; u < 512; u += NWORK) {
      int c = u >> 6, r2 = u & 63, b = r2 >> 3, sub = r2 & 7;
      int row0 = b*512 + c*64 + sub*8;
      if (tid < 256) {
        int r = tid >> 5, c4 = (tid & 31) << 2;
        int tok = jin[row0 + r];
        *(float4*)&arow[r][c4] = *(const float4*)&emb[(size_t)tok*HH + c4];
      }
      __syncthreads();
      const float* w0 = WihE + (size_t)tid*HH;
      float acc[8];
      #pragma unroll
      for (int r=0;r<8;r++) acc[r] = 0.f;
      for (int k=0;k<HH;k+=4) {
        float4 wa = *(const float4*)&w0[k];
        #pragma unroll
        for (int r=0;r<8;r++) {
          float4 av = *(const float4*)&arow[r][k];
          acc[r] += av.x*wa.x + av.y*wa.y + av.z*wa.z + av.w*wa.w;
        }
      }
      float bb = bE[tid];
      #pragma unroll
      for (int r=0;r<8;r++)
        xg[(size_t)(row0+r)*512 + tid] = acc[r] + bb;
      __threadfence();
      __syncthreads();
      if (tid == 0)
        __hip_atomic_fetch_add(&ucnt[(b*8+c)*32], 1, __ATOMIC_RELEASE, __HIP_MEMORY_SCOPE_AGENT);
      __syncthreads();                           // arow reuse guard
    }
    // P0b: split Wo -> (bf16 hi, lo)
    for (int i = wbid*512 + tid; i < VV*HH/4; i += NWORK*512) {
      float4 v = *(const float4*)&Wo[i*4];
      float vv[4] = {v.x, v.y, v.z, v.w};
      #pragma unroll
      for (int k=0;k<4;k++) {
        __hip_bfloat16 h = __float2bfloat16(vv[k]);
        Bhi[i*4+k] = h;
        Blo[i*4+k] = __float2bfloat16(vv[k] - __bfloat162float(h));
      }
    }
    workers_barrier(bar, tid);
    // P1: degree
    for (int i = wbid*512 + tid; i < NEDGE; i += NWORK*512)
      atomicAdd(&deg[edst[i]], 1.0f);
    workers_barrier(bar, tid);
    // P2: dinv
    for (int n = wbid*512 + tid; n < NNODE; n += NWORK*512)
      dinv[n] = 1.0f / sqrtf(deg[n] + 1.0f);
    workers_barrier(bar, tid);
    // P3: s1
    for (int i = wbid*512 + tid; i < NEDGE; i += NWORK*512)
      atomicAdd(&s1[esrc[i]], dinv[edst[i]]);
    workers_barrier(bar, tid);
    // P4: cc + csum
    {
      float lsum = 0.f;
      for (int n = wbid*512 + tid; n < NNODE; n += NWORK*512) {
        float d = dinv[n]; float v = d*s1[n] + d*d; cc[n] = v; lsum += v;
      }
      red[tid] = lsum; __syncthreads();
      for (int sfl=256; sfl>0; sfl>>=1) { if (tid < sfl) red[tid] += red[tid+sfl]; __syncthreads(); }
      if (tid==0) atomicAdd(csum, red[0]);
    }
    workers_barrier(bar, tid);
    // P5: s2
    for (int i = wbid*512 + tid; i < NEDGE; i += NWORK*512) {
      int d = edst[i]; atomicAdd(&s2[esrc[i]], cc[d]*dinv[d]);
    }
    workers_barrier(bar, tid);
    // P6: ee
    for (int n = wbid*512 + tid; n < NNODE; n += NWORK*512) {
      float d = dinv[n]; ee[n] = d*s2[n] + cc[n]*d*d;
    }
    workers_barrier(bar, tid);
    // P7: gvec[j] = sum_n ee[n]*emb[nids[n]][j]
    {
      int j = tid & 127, sub = tid >> 7;         // 4 n-lanes per block
      float acc = 0.f;
      for (int n = wbid*4 + sub; n < NNODE; n += NWORK*4)
        acc += ee[n] * emb[(size_t)nids[n]*HH + j];
      red[tid] = acc; __syncthreads();
      if (tid < 128) atomicAdd(&gvec[j], red[tid] + red[tid+128] + red[tid+256] + red[tid+384]);
    }
    workers_barrier(bar, tid);
    // P8: graph final (one block)
    if (wbid == 0 && tid < 128) {
      float* gs = (float*)shraw;
      float* v1 = gs + 128;
      int j = tid;
      gs[j] = gvec[j];
      __builtin_amdgcn_s_barrier();
      float a = 0.f;
      for (int k=0;k<128;k++) a += gs[k]*W1[j*128+k];
      v1[j] = a + csum[0]*b1[j];
      __builtin_amdgcn_s_barrier();
      float a2 = 0.f;
      for (int k=0;k<128;k++) a2 += v1[k]*W2[j*128+k];
      mvec[j] = a2 * (1.0f/(float)NNODE) + b2[j];
    }
  }
}

// ---------------- FUSED decoder scan + output GEMM (8 chunks, 64-row tiles) ----
__global__ __launch_bounds__(512) void dec_gemm_kernel(
    const float* __restrict__ xgdec, const float* __restrict__ Whh,
    __hip_bfloat16* __restrict__ ahi, __hip_bfloat16* __restrict__ alo,
    const __hip_bfloat16* __restrict__ Bhi, const __hip_bfloat16* __restrict__ Blo,
    const float* __restrict__ bo, float* __restrict__ out, int* __restrict__ prog)
{
  __shared__ __align__(16) char shraw[131072];   // 128KB -> 1 block/CU
  const int bid = blockIdx.x, tid = threadIdx.x;

  if (bid < 8) {
    // ---------------- decoder scan role (round-4 body) ----------------
    float* h_s   = (float*)shraw;
    float* act_s = ((float*)shraw) + 128;
    const int b = bid;

    const f32x4* Wrow = (const f32x4*)(Whh + (size_t)tid*HH);
    f32x4 w[32];
    #pragma unroll
    for (int k=0;k<32;k++) w[k] = Wrow[k];
    #pragma unroll
    for (int k=0;k<32;k++) asm volatile("" : "+v"(w[k]));

    float xv = xgdec[b*512 + tid];
    if (tid < 128) h_s[tid] = 0.f;
    float cstate = 0.f;
    __syncthreads();

    for (int t=0;t<SS;t++) {
      float a0=0.f,a1=0.f,a2=0.f,a3=0.f;
      #pragma unroll
      for (int k=0;k<32;k++) {
        f32x4 hv = *(const f32x4*)&h_s[k*4];
        a0 += w[k].x*hv.x; a1 += w[k].y*hv.y;
        a2 += w[k].z*hv.z; a3 += w[k].w*hv.w;
      }
      float s = (a0+a1)+(a2+a3) + xv;
      int gid = tid >> 7;
      float act = (gid==2) ? tanhf(s) : 1.0f/(1.0f+expf(-s));
      act_s[tid] = act;
      __syncthreads();
      if (tid < 128) {
        float i_ = act_s[tid], f_ = act_s[128+tid], g_ = act_s[256+tid], o_ = act_s[384+tid];
        cstate = f_*cstate + i_*g_;
        float hh = o_*tanhf(cstate);
        h_s[tid] = hh;
        size_t row = (size_t)b*SS + t;
        __hip_bfloat16 hi = __float2bfloat16(hh);
        float rem = hh - __bfloat162float(hi);
        ahi[row*HH + tid] = hi;
        alo[row*HH + tid] = __float2bfloat16(rem);
      }
      __syncthreads();
      if ((t & 63) == 63) {                     // publish completed 64-step chunk
        __threadfence();
        __syncthreads();
        if (tid == 0)
          __hip_atomic_store(&prog[b*32], (t >> 6) + 1,
                             __ATOMIC_RELEASE, __HIP_MEMORY_SCOPE_AGENT);
      }
    }
  } else {
    // ---------------- gemm role: one 64x256 output tile ----------------
    short* smem = (short*)shraw;                // hi plane @0, lo plane @64KB
    const int gbid = bid - 8;
    const int c    = gbid / 1000;               // chunk-major: c = 0..7
    const int r    = gbid % 1000;
    const int b    = r / 125;                   // batch
    const int nblk = r % 125;                   // 256-col tile
    const int mbase0 = b*512 + c*64;            // 64 rows of this chunk

    if (tid == 0) {                             // single-lane, slow poll
      while (__hip_atomic_load(&prog[b*32], __ATOMIC_ACQUIRE,
                               __HIP_MEMORY_SCOPE_AGENT) <= c)
        __builtin_amdgcn_s_sleep(64);
    }
    __syncthreads();

    // stage B tile (256 cols x 128 k, hi+lo) into LDS, inverse-swizzled source
    const short* bsrc[2] = {
      (const short*)Bhi + (size_t)nblk*256*HH,
      (const short*)Blo + (size_t)nblk*256*HH };
    #pragma unroll
    for (int p=0;p<2;p++) {
      #pragma unroll
      for (int it=0; it<8; it++) {
        int off  = it*8192 + tid*16;
        int row  = off >> 8;
        int soff = off ^ ((row & 15) << 4);
        __builtin_amdgcn_global_load_lds(
          (const __attribute__((address_space(1))) void*)((const char*)bsrc[p] + soff),
          (__attribute__((address_space(3))) void*)((char*)smem + p*65536 + off),
          16, 0, 0);
      }
    }
    __syncthreads();

    const int lane = tid & 63;
    const int wid  = tid >> 6;
    const int wm = wid >> 2, wn = wid & 3;      // 2m x 4n waves: 32x64 each
    const int l15 = lane & 15, l4 = lane >> 4;
    const int mbase = mbase0 + wm*32;
    const short* Ah = (const short*)ahi;
    const short* Al = (const short*)alo;

    f32x4 acc[2][4] = {};
    #pragma unroll
    for (int s=0;s<4;s++) {
      s16x8 bh[4], bl[4], ah[2], al[2];
      #pragma unroll
      for (int qn=0;qn<4;qn++) {
        int rb   = wn*64 + qn*16 + l15;
        int offb = (rb*256 + s*64 + l4*16) ^ ((rb & 15) << 4);
        bh[qn] = *(const s16x8*)((const char*)smem + offb);
        bl[qn] = *(const s16x8*)((const char*)smem + 65536 + offb);
      }
      #pragma unroll
      for (int qm=0;qm<2;qm++) {
        int arow = mbase + qm*16 + l15;
        size_t aoff = (size_t)arow*HH + s*32 + l4*8;
        ah[qm] = *(const s16x8*)(Ah + aoff);    // A direct from global (L2-hot)
        al[qm] = *(const s16x8*)(Al + aoff);
      }
      #pragma unroll
      for (int qm=0;qm<2;qm++) {
        #pragma unroll
        for (int qn=0;qn<4;qn++) {
          acc[qm][qn] = __builtin_amdgcn_mfma_f32_16x16x32_bf16(bh[qn], ah[qm], acc[qm][qn], 0,0,0);
          acc[qm][qn] = __builtin_amdgcn_mfma_f32_16x16x32_bf16(bl[qn], ah[qm], acc[qm][qn], 0,0,0);
          acc[qm][qn] = __builtin_amdgcn_mfma_f32_16x16x32_bf16(bh[qn], al[qm], acc[qm][qn], 0,0,0);
        }
      }
    }
    #pragma unroll
    for (int qm=0;qm<2;qm++) {
      int row = mbase + qm*16 + l15;            // swapped C/D: l15 = M-row
      #pragma unroll
      for (int qn=0;qn<4;qn++) {
        int colb = nblk*256 + wn*64 + qn*16 + l4*4;
        f32x4 bv = *(const f32x4*)&bo[colb];
        f32x4 o = acc[qm][qn] + bv;
        *(f32x4*)&out[(size_t)row*VV + colb] = o;
      }
    }
  }
}

// ---------------- fusion ----------------
__global__ __launch_bounds__(512) void fusion_kernel(const float* __restrict__ hmean, const float* __restrict__ mvec,
    const float* __restrict__ Wf, const float* __restrict__ bfv,
    const float* __restrict__ Wihd, const float* __restrict__ bd, float* __restrict__ xgdec)
{
  __shared__ float comb[256];
  __shared__ float fus[128];
  int b = blockIdx.x, tid = threadIdx.x;
  if (tid < 128) comb[tid] = hmean[b*128 + tid];
  else if (tid < 256) comb[tid] = mvec[tid - 128];
  __syncthreads();
  if (tid < 128) {
    float a = 0.f;
    for (int k=0;k<256;k++) a += comb[k]*Wf[tid*256+k];
    fus[tid] = a + bfv[tid];
  }
  __syncthreads();
  float a = 0.f;
  for (int k=0;k<128;k++) a += fus[k]*Wihd[tid*128+k];
  xgdec[b*512 + tid] = a + bd[tid];
}

// ---------------- launch ----------------
extern "C" void kernel_launch(void* const* d_in, const int* in_sizes, int n_in,
                              void* d_out, int out_size, void* d_ws, size_t ws_size,
                              hipStream_t stream)
{
  (void)in_sizes; (void)n_in; (void)out_size; (void)ws_size;
  const int*   jin   = (const int*)d_in[0];
  const int*   nids  = (const int*)d_in[1];
  const int*   esrc  = (const int*)d_in[2];
  const int*   edst  = esrc + NEDGE;
  const float* emb   = (const float*)d_in[3];
  const float* WihE  = (const float*)d_in[4];
  const float* WhhE  = (const float*)d_in[5];
  const float* bE    = (const float*)d_in[6];
  const float* W1    = (const float*)d_in[7];
  const float* b1    = (const float*)d_in[8];
  const float* W2    = (const float*)d_in[9];
  const float* b2    = (const float*)d_in[10];
  const float* Wf    = (const float*)d_in[11];
  const float* bfv   = (const float*)d_in[12];
  const float* WihD  = (const float*)d_in[13];
  const float* WhhD  = (const float*)d_in[14];
  const float* bD    = (const float*)d_in[15];
  const float* Wo    = (const float*)d_in[16];
  const float* bo    = (const float*)d_in[17];
  float* out = (float*)d_out;

  char* ws = (char*)d_ws;
  size_t off = 0;
  auto alloc = [&](size_t bytes) { size_t o = off; off = (off + bytes + 255) & ~(size_t)255; return o; };

  int*   prog = (int*)(ws + alloc(BB*32*4));       // decoder progress (line/batch)
  int*   ucnt = (int*)(ws + alloc(BB*8*32*4));     // xg unit counters (line/(b,c))
  int*   bar  = (int*)(ws + alloc(64*4));          // workers barrier cnt/gen
  float* deg  = (float*)(ws + alloc(NNODE*4));
  float* s1   = (float*)(ws + alloc(NNODE*4));
  float* s2   = (float*)(ws + alloc(NNODE*4));
  float* gvec = (float*)(ws + alloc(128*4));
  float* csum = (float*)(ws + alloc(4));
  size_t zero_bytes = off;
  float* dinv = (float*)(ws + alloc(NNODE*4));
  float* cc   = (float*)(ws + alloc(NNODE*4));
  float* ee   = (float*)(ws + alloc(NNODE*4));
  float* mvec = (float*)(ws + alloc(128*4));
  float* hmean= (float*)(ws + alloc(BB*HH*4));
  float* xgdec= (float*)(ws + alloc(BB*512*4));
  float* xgenc= (float*)(ws + alloc((size_t)BB*SS*512*4));
  __hip_bfloat16* Ahi = (__hip_bfloat16*)(ws + alloc((size_t)BB*SS*HH*2));
  __hip_bfloat16* Alo = (__hip_bfloat16*)(ws + alloc((size_t)BB*SS*HH*2));
  __hip_bfloat16* Bhi = (__hip_bfloat16*)(ws + alloc((size_t)VV*HH*2));
  __hip_bfloat16* Blo = (__hip_bfloat16*)(ws + alloc((size_t)VV*HH*2));

  hipMemsetAsync(ws, 0, zero_bytes, stream);

  // front: enc scan + {xg production, Wo split, graph pipeline} on idle CUs
  front_kernel<<<dim3(8 + NWORK), dim3(512), 0, stream>>>(
      jin, emb, WihE, bE, xgenc, WhhE, hmean, Wo, Bhi, Blo,
      esrc, edst, nids, deg, dinv, s1, s2, cc, ee, csum, gvec,
      W1, b1, W2, b2, mvec, ucnt, bar);

  // fusion, then fused decoder-scan + output-GEMM (gemm hidden under the scan)
  fusion_kernel<<<dim3(BB), dim3(512), 0, stream>>>(hmean, mvec, Wf, bfv, WihD, bD, xgdec);
  dec_gemm_kernel<<<dim3(8 + 8000), dim3(512), 0, stream>>>(
      xgdec, WhhD, Ahi, Alo, Bhi, Blo, bo, out, prog);
}

// Round 15
// 1175.572 us; speedup vs baseline: 3.6856x; 1.0649x over previous
//
#include <hip/hip_runtime.h>
#include <hip/hip_bf16.h>
#include <stdint.h>

#define VV 32000
#define HH 128
#define BB 8
#define SS 512
#define NNODE 50000
#define NEDGE 600000
#define NWORK 240          // worker blocks in front kernel (248 total <= 256 CUs)

typedef __attribute__((ext_vector_type(8))) short s16x8;
typedef __attribute__((ext_vector_type(4))) float f32x4;

__device__ __forceinline__ void workers_barrier(int* bar, int tid) {
  __syncthreads();
  if (tid == 0) {
    int g = __hip_atomic_load(&bar[32], __ATOMIC_ACQUIRE, __HIP_MEMORY_SCOPE_AGENT);
    int old = __hip_atomic_fetch_add(&bar[0], 1, __ATOMIC_ACQ_REL, __HIP_MEMORY_SCOPE_AGENT);
    if (old == NWORK-1) {
      __hip_atomic_store(&bar[0], 0, __ATOMIC_RELAXED, __HIP_MEMORY_SCOPE_AGENT);
      __hip_atomic_store(&bar[32], g+1, __ATOMIC_RELEASE, __HIP_MEMORY_SCOPE_AGENT);
    } else {
      while (__hip_atomic_load(&bar[32], __ATOMIC_ACQUIRE, __HIP_MEMORY_SCOPE_AGENT) == g)
        __builtin_amdgcn_s_sleep(32);
    }
  }
  __syncthreads();
}

// ---------------- embedding gather + encoder input-gate GEMM (serial, ~20us) ----
__global__ __launch_bounds__(256) void xg_enc_kernel(
    const int* __restrict__ jin, const float* __restrict__ emb,
    const float* __restrict__ Wih, const float* __restrict__ bvec,
    float* __restrict__ xg)
{
  __shared__ __align__(16) float arow[8][128];
  const int tid = threadIdx.x, blk = blockIdx.x;
  {
    int r = tid >> 5, c = (tid & 31) << 2;
    int tok = jin[blk*8 + r];
    *(float4*)&arow[r][c] = *(const float4*)&emb[(size_t)tok*HH + c];
  }
  __syncthreads();
  const int g0 = tid * 2;
  const float* w0 = Wih + (size_t)g0*HH;
  const float* w1 = w0 + HH;
  float acc0[8], acc1[8];
  #pragma unroll
  for (int r=0;r<8;r++){ acc0[r]=0.f; acc1[r]=0.f; }
  for (int k=0;k<HH;k+=4) {
    float4 wa = *(const float4*)&w0[k];
    float4 wb = *(const float4*)&w1[k];
    #pragma unroll
    for (int r=0;r<8;r++) {
      float4 av = *(const float4*)&arow[r][k];
      acc0[r] += av.x*wa.x + av.y*wa.y + av.z*wa.z + av.w*wa.w;
      acc1[r] += av.x*wb.x + av.y*wb.y + av.z*wb.z + av.w*wb.w;
    }
  }
  float bb0 = bvec[g0], bb1 = bvec[g0+1];
  #pragma unroll
  for (int r=0;r<8;r++) {
    size_t row = (size_t)blk*8 + r;
    xg[row*512 + g0]     = acc0[r] + bb0;
    xg[row*512 + g0 + 1] = acc1[r] + bb1;
  }
}

// ---------------- FRONT: clean enc scan (blocks 0-7) + workers (split + graph) ----
__global__ __launch_bounds__(512) void front_kernel(
    const float* __restrict__ xg, const float* __restrict__ WhhE, float* __restrict__ hmean,
    const float* __restrict__ Wo, __hip_bfloat16* __restrict__ Bhi, __hip_bfloat16* __restrict__ Blo,
    const int* __restrict__ esrc, const int* __restrict__ edst, const int* __restrict__ nids,
    const float* __restrict__ emb,
    float* __restrict__ deg, float* __restrict__ dinv, float* __restrict__ s1,
    float* __restrict__ s2, float* __restrict__ cc, float* __restrict__ ee,
    float* __restrict__ csum, float* __restrict__ gvec,
    const float* __restrict__ W1, const float* __restrict__ b1,
    const float* __restrict__ W2, const float* __restrict__ b2, float* __restrict__ mvec,
    int* bar)
{
  __shared__ __align__(16) char shraw[131072];   // 128KB -> 1 block/CU (isolation)
  const int bid = blockIdx.x, tid = threadIdx.x;

  if (bid < 8) {
    // ---------------- encoder scan role (round-4 proven body, ungated) --------
    float* h_s   = (float*)shraw;
    float* act_s = ((float*)shraw) + 128;
    const int b = bid;

    const f32x4* Wrow = (const f32x4*)(WhhE + (size_t)tid*HH);
    f32x4 w[32];
    #pragma unroll
    for (int k=0;k<32;k++) w[k] = Wrow[k];
    #pragma unroll
    for (int k=0;k<32;k++) asm volatile("" : "+v"(w[k]));

    const float* xgrow = xg + (size_t)b*SS*512;
    float xv = xgrow[tid];
    if (tid < 128) h_s[tid] = 0.f;
    float cstate = 0.f, hsum = 0.f;
    __syncthreads();

    for (int t=0;t<SS;t++) {
      int tn = (t < SS-1) ? (t+1) : t;
      float nxv = xgrow[(size_t)tn*512 + tid];
      float a0=0.f,a1=0.f,a2=0.f,a3=0.f;
      #pragma unroll
      for (int k=0;k<32;k++) {
        f32x4 hv = *(const f32x4*)&h_s[k*4];
        a0 += w[k].x*hv.x; a1 += w[k].y*hv.y;
        a2 += w[k].z*hv.z; a3 += w[k].w*hv.w;
      }
      float s = (a0+a1)+(a2+a3) + xv;
      int gid = tid >> 7;
      float act = (gid==2) ? tanhf(s) : 1.0f/(1.0f+expf(-s));
      act_s[tid] = act;
      __syncthreads();
      if (tid < 128) {
        float i_ = act_s[tid], f_ = act_s[128+tid], g_ = act_s[256+tid], o_ = act_s[384+tid];
        cstate = f_*cstate + i_*g_;
        float hh = o_*tanhf(cstate);
        h_s[tid] = hh;
        hsum += hh;
      }
      xv = nxv;
      __syncthreads();
    }
    if (tid < 128) hmean[b*HH + tid] = hsum * (1.0f/512.0f);
  } else {
    // ---------------- worker role: Wo split + graph pipeline ------------------
    const int wbid = bid - 8;
    float* red = (float*)shraw;                  // 512 reduce scratch

    // P0: split Wo -> (bf16 hi, lo)
    for (int i = wbid*512 + tid; i < VV*HH/4; i += NWORK*512) {
      float4 v = *(const float4*)&Wo[i*4];
      float vv[4] = {v.x, v.y, v.z, v.w};
      #pragma unroll
      for (int k=0;k<4;k++) {
        __hip_bfloat16 h = __float2bfloat16(vv[k]);
        Bhi[i*4+k] = h;
        Blo[i*4+k] = __float2bfloat16(vv[k] - __bfloat162float(h));
      }
    }
    workers_barrier(bar, tid);
    // P1: degree
    for (int i = wbid*512 + tid; i < NEDGE; i += NWORK*512)
      atomicAdd(&deg[edst[i]], 1.0f);
    workers_barrier(bar, tid);
    // P2: dinv
    for (int n = wbid*512 + tid; n < NNODE; n += NWORK*512)
      dinv[n] = 1.0f / sqrtf(deg[n] + 1.0f);
    workers_barrier(bar, tid);
    // P3: s1
    for (int i = wbid*512 + tid; i < NEDGE; i += NWORK*512)
      atomicAdd(&s1[esrc[i]], dinv[edst[i]]);
    workers_barrier(bar, tid);
    // P4: cc + csum
    {
      float lsum = 0.f;
      for (int n = wbid*512 + tid; n < NNODE; n += NWORK*512) {
        float d = dinv[n]; float v = d*s1[n] + d*d; cc[n] = v; lsum += v;
      }
      red[tid] = lsum; __syncthreads();
      for (int sfl=256; sfl>0; sfl>>=1) { if (tid < sfl) red[tid] += red[tid+sfl]; __syncthreads(); }
      if (tid==0) atomicAdd(csum, red[0]);
    }
    workers_barrier(bar, tid);
    // P5: s2
    for (int i = wbid*512 + tid; i < NEDGE; i += NWORK*512) {
      int d = edst[i]; atomicAdd(&s2[esrc[i]], cc[d]*dinv[d]);
    }
    workers_barrier(bar, tid);
    // P6: ee
    for (int n = wbid*512 + tid; n < NNODE; n += NWORK*512) {
      float d = dinv[n]; ee[n] = d*s2[n] + cc[n]*d*d;
    }
    workers_barrier(bar, tid);
    // P7: gvec[j] = sum_n ee[n]*emb[nids[n]][j]
    {
      int j = tid & 127, sub = tid >> 7;         // 4 n-lanes per block
      float acc = 0.f;
      for (int n = wbid*4 + sub; n < NNODE; n += NWORK*4)
        acc += ee[n] * emb[(size_t)nids[n]*HH + j];
      red[tid] = acc; __syncthreads();
      if (tid < 128) atomicAdd(&gvec[j], red[tid] + red[tid+128] + red[tid+256] + red[tid+384]);
    }
    workers_barrier(bar, tid);
    // P8: graph final (block 0, full-block barriers)
    if (wbid == 0) {
      float* gs = (float*)shraw;
      float* v1 = gs + 128;
      if (tid < 128) gs[tid] = gvec[tid];
      __syncthreads();
      if (tid < 128) {
        float a = 0.f;
        for (int k=0;k<128;k++) a += gs[k]*W1[tid*128+k];
        v1[tid] = a + csum[0]*b1[tid];
      }
      __syncthreads();
      if (tid < 128) {
        float a2 = 0.f;
        for (int k=0;k<128;k++) a2 += v1[k]*W2[tid*128+k];
        mvec[tid] = a2 * (1.0f/(float)NNODE) + b2[tid];
      }
    }
  }
}

// ---------------- FUSED decoder scan + PERSISTENT-owner output GEMM ----------
// Blocks 0-7: decoder scan (round-4 body), publish prog[b*32] every 64 steps.
// Blocks 8..247: persistent owners. Owner o<230: nblk=o/2, batches (o&1)*4..+4;
// o>=230: nblk=115+(o-230), all 8 batches. B panel (256 cols, hi+lo) staged
// ONCE into 128KB LDS, then loop (chunk, batch) tiles as published.
// B traffic: 1GB -> 30MB vs round-14.
__global__ __launch_bounds__(512) void dec_gemm_kernel(
    const float* __restrict__ xgdec, const float* __restrict__ Whh,
    __hip_bfloat16* __restrict__ ahi, __hip_bfloat16* __restrict__ alo,
    const __hip_bfloat16* __restrict__ Bhi, const __hip_bfloat16* __restrict__ Blo,
    const float* __restrict__ bo, float* __restrict__ out, int* __restrict__ prog)
{
  __shared__ __align__(16) char shraw[131072];   // 128KB -> 1 block/CU
  const int bid = blockIdx.x, tid = threadIdx.x;

  if (bid < 8) {
    // ---------------- decoder scan role (round-4 body) ----------------
    float* h_s   = (float*)shraw;
    float* act_s = ((float*)shraw) + 128;
    const int b = bid;

    const f32x4* Wrow = (const f32x4*)(Whh + (size_t)tid*HH);
    f32x4 w[32];
    #pragma unroll
    for (int k=0;k<32;k++) w[k] = Wrow[k];
    #pragma unroll
    for (int k=0;k<32;k++) asm volatile("" : "+v"(w[k]));

    float xv = xgdec[b*512 + tid];
    if (tid < 128) h_s[tid] = 0.f;
    float cstate = 0.f;
    __syncthreads();

    for (int t=0;t<SS;t++) {
      float a0=0.f,a1=0.f,a2=0.f,a3=0.f;
      #pragma unroll
      for (int k=0;k<32;k++) {
        f32x4 hv = *(const f32x4*)&h_s[k*4];
        a0 += w[k].x*hv.x; a1 += w[k].y*hv.y;
        a2 += w[k].z*hv.z; a3 += w[k].w*hv.w;
      }
      float s = (a0+a1)+(a2+a3) + xv;
      int gid = tid >> 7;
      float act = (gid==2) ? tanhf(s) : 1.0f/(1.0f+expf(-s));
      act_s[tid] = act;
      __syncthreads();
      if (tid < 128) {
        float i_ = act_s[tid], f_ = act_s[128+tid], g_ = act_s[256+tid], o_ = act_s[384+tid];
        cstate = f_*cstate + i_*g_;
        float hh = o_*tanhf(cstate);
        h_s[tid] = hh;
        size_t row = (size_t)b*SS + t;
        __hip_bfloat16 hi = __float2bfloat16(hh);
        float rem = hh - __bfloat162float(hi);
        ahi[row*HH + tid] = hi;
        alo[row*HH + tid] = __float2bfloat16(rem);
      }
      __syncthreads();
      if ((t & 63) == 63) {                     // publish completed 64-step chunk
        __threadfence();
        __syncthreads();
        if (tid == 0)
          __hip_atomic_store(&prog[b*32], (t >> 6) + 1,
                             __ATOMIC_RELEASE, __HIP_MEMORY_SCOPE_AGENT);
      }
    }
  } else {
    // ---------------- persistent gemm owner ----------------
    short* smem = (short*)shraw;                // hi plane @0, lo plane @64KB
    const int o = bid - 8;                      // 0..239
    int nblk, b0, nb;
    if (o < 230) { nblk = o >> 1; b0 = (o & 1) * 4; nb = 4; }
    else         { nblk = 115 + (o - 230); b0 = 0; nb = 8; }

    // stage B panel once (256 cols x 128 k, hi+lo), inverse-swizzled source
    const short* bsrc[2] = {
      (const short*)Bhi + (size_t)nblk*256*HH,
      (const short*)Blo + (size_t)nblk*256*HH };
    #pragma unroll
    for (int p=0;p<2;p++) {
      #pragma unroll
      for (int it=0; it<8; it++) {
        int off  = it*8192 + tid*16;
        int row  = off >> 8;
        int soff = off ^ ((row & 15) << 4);
        __builtin_amdgcn_global_load_lds(
          (const __attribute__((address_space(1))) void*)((const char*)bsrc[p] + soff),
          (__attribute__((address_space(3))) void*)((char*)smem + p*65536 + off),
          16, 0, 0);
      }
    }
    __syncthreads();

    const int lane = tid & 63;
    const int wid  = tid >> 6;
    const int wm = wid >> 2, wn = wid & 3;      // 2m x 4n waves: 32x64 each
    const int l15 = lane & 15, l4 = lane >> 4;
    const short* Ah = (const short*)ahi;
    const short* Al = (const short*)alo;

    for (int c = 0; c < 8; ++c) {
      for (int bi = 0; bi < nb; ++bi) {
        int b = b0 + bi;
        if (tid == 0) {                         // single-lane, slow poll
          while (__hip_atomic_load(&prog[b*32], __ATOMIC_ACQUIRE,
                                   __HIP_MEMORY_SCOPE_AGENT) <= c)
            __builtin_amdgcn_s_sleep(64);
        }
        __syncthreads();

        const int mbase = b*512 + c*64 + wm*32;
        f32x4 acc[2][4] = {};
        #pragma unroll
        for (int s=0;s<4;s++) {
          s16x8 bh[4], bl[4], ah[2], al[2];
          #pragma unroll
          for (int qn=0;qn<4;qn++) {
            int rb   = wn*64 + qn*16 + l15;
            int offb = (rb*256 + s*64 + l4*16) ^ ((rb & 15) << 4);
            bh[qn] = *(const s16x8*)((const char*)smem + offb);
            bl[qn] = *(const s16x8*)((const char*)smem + 65536 + offb);
          }
          #pragma unroll
          for (int qm=0;qm<2;qm++) {
            int arow = mbase + qm*16 + l15;
            size_t aoff = (size_t)arow*HH + s*32 + l4*8;
            ah[qm] = *(const s16x8*)(Ah + aoff);    // A direct from global (L2-hot)
            al[qm] = *(const s16x8*)(Al + aoff);
          }
          #pragma unroll
          for (int qm=0;qm<2;qm++) {
            #pragma unroll
            for (int qn=0;qn<4;qn++) {
              acc[qm][qn] = __builtin_amdgcn_mfma_f32_16x16x32_bf16(bh[qn], ah[qm], acc[qm][qn], 0,0,0);
              acc[qm][qn] = __builtin_amdgcn_mfma_f32_16x16x32_bf16(bl[qn], ah[qm], acc[qm][qn], 0,0,0);
              acc[qm][qn] = __builtin_amdgcn_mfma_f32_16x16x32_bf16(bh[qn], al[qm], acc[qm][qn], 0,0,0);
            }
          }
        }
        #pragma unroll
        for (int qm=0;qm<2;qm++) {
          int row = mbase + qm*16 + l15;        // swapped C/D: l15 = M-row
          #pragma unroll
          for (int qn=0;qn<4;qn++) {
            int colb = nblk*256 + wn*64 + qn*16 + l4*4;
            f32x4 bv = *(const f32x4*)&bo[colb];
            f32x4 oo = acc[qm][qn] + bv;
            *(f32x4*)&out[(size_t)row*VV + colb] = oo;
          }
        }
      }
    }
  }
}

// ---------------- fusion ----------------
__global__ __launch_bounds__(512) void fusion_kernel(const float* __restrict__ hmean, const float* __restrict__ mvec,
    const float* __restrict__ Wf, const float* __restrict__ bfv,
    const float* __restrict__ Wihd, const float* __restrict__ bd, float* __restrict__ xgdec)
{
  __shared__ float comb[256];
  __shared__ float fus[128];
  int b = blockIdx.x, tid = threadIdx.x;
  if (tid < 128) comb[tid] = hmean[b*128 + tid];
  else if (tid < 256) comb[tid] = mvec[tid - 128];
  __syncthreads();
  if (tid < 128) {
    float a = 0.f;
    for (int k=0;k<256;k++) a += comb[k]*Wf[tid*256+k];
    fus[tid] = a + bfv[tid];
  }
  __syncthreads();
  float a = 0.f;
  for (int k=0;k<128;k++) a += fus[k]*Wihd[tid*128+k];
  xgdec[b*512 + tid] = a + bd[tid];
}

// ---------------- launch ----------------
extern "C" void kernel_launch(void* const* d_in, const int* in_sizes, int n_in,
                              void* d_out, int out_size, void* d_ws, size_t ws_size,
                              hipStream_t stream)
{
  (void)in_sizes; (void)n_in; (void)out_size; (void)ws_size;
  const int*   jin   = (const int*)d_in[0];
  const int*   nids  = (const int*)d_in[1];
  const int*   esrc  = (const int*)d_in[2];
  const int*   edst  = esrc + NEDGE;
  const float* emb   = (const float*)d_in[3];
  const float* WihE  = (const float*)d_in[4];
  const float* WhhE  = (const float*)d_in[5];
  const float* bE    = (const float*)d_in[6];
  const float* W1    = (const float*)d_in[7];
  const float* b1    = (const float*)d_in[8];
  const float* W2    = (const float*)d_in[9];
  const float* b2    = (const float*)d_in[10];
  const float* Wf    = (const float*)d_in[11];
  const float* bfv   = (const float*)d_in[12];
  const float* WihD  = (const float*)d_in[13];
  const float* WhhD  = (const float*)d_in[14];
  const float* bD    = (const float*)d_in[15];
  const float* Wo    = (const float*)d_in[16];
  const float* bo    = (const float*)d_in[17];
  float* out = (float*)d_out;

  char* ws = (char*)d_ws;
  size_t off = 0;
  auto alloc = [&](size_t bytes) { size_t o = off; off = (off + bytes + 255) & ~(size_t)255; return o; };

  int*   prog = (int*)(ws + alloc(BB*32*4));       // decoder progress (line/batch)
  int*   bar  = (int*)(ws + alloc(64*4));          // workers barrier cnt/gen
  float* deg  = (float*)(ws + alloc(NNODE*4));
  float* s1   = (float*)(ws + alloc(NNODE*4));
  float* s2   = (float*)(ws + alloc(NNODE*4));
  float* gvec = (float*)(ws + alloc(128*4));
  float* csum = (float*)(ws + alloc(4));
  size_t zero_bytes = off;
  float* dinv = (float*)(ws + alloc(NNODE*4));
  float* cc   = (float*)(ws + alloc(NNODE*4));
  float* ee   = (float*)(ws + alloc(NNODE*4));
  float* mvec = (float*)(ws + alloc(128*4));
  float* hmean= (float*)(ws + alloc(BB*HH*4));
  float* xgdec= (float*)(ws + alloc(BB*512*4));
  float* xgenc= (float*)(ws + alloc((size_t)BB*SS*512*4));
  __hip_bfloat16* Ahi = (__hip_bfloat16*)(ws + alloc((size_t)BB*SS*HH*2));
  __hip_bfloat16* Alo = (__hip_bfloat16*)(ws + alloc((size_t)BB*SS*HH*2));
  __hip_bfloat16* Bhi = (__hip_bfloat16*)(ws + alloc((size_t)VV*HH*2));
  __hip_bfloat16* Blo = (__hip_bfloat16*)(ws + alloc((size_t)VV*HH*2));

  hipMemsetAsync(ws, 0, zero_bytes, stream);

  // serial xg production (tiny, ~20us) — keeps Wih hammering off the front kernel
  xg_enc_kernel<<<dim3((BB*SS)/8), dim3(256), 0, stream>>>(jin, emb, WihE, bE, xgenc);

  // front: clean enc scan + {Wo split, graph pipeline} on idle CUs
  front_kernel<<<dim3(8 + NWORK), dim3(512), 0, stream>>>(
      xgenc, WhhE, hmean, Wo, Bhi, Blo,
      esrc, edst, nids, emb, deg, dinv, s1, s2, cc, ee, csum, gvec,
      W1, b1, W2, b2, mvec, bar);

  // fusion, then fused decoder-scan + persistent-owner GEMM
  fusion_kernel<<<dim3(BB), dim3(512), 0, stream>>>(hmean, mvec, Wf, bfv, WihD, bD, xgdec);
  dec_gemm_kernel<<<dim3(8 + NWORK), dim3(512), 0, stream>>>(
      xgdec, WhhD, Ahi, Alo, Bhi, Blo, bo, out, prog);
}

// Round 17
// 1118.526 us; speedup vs baseline: 3.8736x; 1.0510x over previous
//
#include <hip/hip_runtime.h>
#include <hip/hip_bf16.h>
#include <stdint.h>

#define VV 32000
#define HH 128
#define BB 8
#define SS 512
#define NNODE 50000
#define NEDGE 600000
#define NWORK 240          // worker blocks in front kernel (248 total <= 256 CUs)

typedef __attribute__((ext_vector_type(8))) short s16x8;
typedef __attribute__((ext_vector_type(4))) float f32x4;

__device__ __forceinline__ void workers_barrier(int* bar, int tid) {
  __syncthreads();
  if (tid == 0) {
    int g = __hip_atomic_load(&bar[32], __ATOMIC_ACQUIRE, __HIP_MEMORY_SCOPE_AGENT);
    int old = __hip_atomic_fetch_add(&bar[0], 1, __ATOMIC_ACQ_REL, __HIP_MEMORY_SCOPE_AGENT);
    if (old == NWORK-1) {
      __hip_atomic_store(&bar[0], 0, __ATOMIC_RELAXED, __HIP_MEMORY_SCOPE_AGENT);
      __hip_atomic_store(&bar[32], g+1, __ATOMIC_RELEASE, __HIP_MEMORY_SCOPE_AGENT);
    } else {
      while (__hip_atomic_load(&bar[32], __ATOMIC_ACQUIRE, __HIP_MEMORY_SCOPE_AGENT) == g)
        __builtin_amdgcn_s_sleep(32);
    }
  }
  __syncthreads();
}

// ---------------- embedding gather + encoder input-gate GEMM (serial, ~20us) ----
__global__ __launch_bounds__(256) void xg_enc_kernel(
    const int* __restrict__ jin, const float* __restrict__ emb,
    const float* __restrict__ Wih, const float* __restrict__ bvec,
    float* __restrict__ xg)
{
  __shared__ __align__(16) float arow[8][128];
  const int tid = threadIdx.x, blk = blockIdx.x;
  {
    int r = tid >> 5, c = (tid & 31) << 2;
    int tok = jin[blk*8 + r];
    *(float4*)&arow[r][c] = *(const float4*)&emb[(size_t)tok*HH + c];
  }
  __syncthreads();
  const int g0 = tid * 2;
  const float* w0 = Wih + (size_t)g0*HH;
  const float* w1 = w0 + HH;
  float acc0[8], acc1[8];
  #pragma unroll
  for (int r=0;r<8;r++){ acc0[r]=0.f; acc1[r]=0.f; }
  for (int k=0;k<HH;k+=4) {
    float4 wa = *(const float4*)&w0[k];
    float4 wb = *(const float4*)&w1[k];
    #pragma unroll
    for (int r=0;r<8;r++) {
      float4 av = *(const float4*)&arow[r][k];
      acc0[r] += av.x*wa.x + av.y*wa.y + av.z*wa.z + av.w*wa.w;
      acc1[r] += av.x*wb.x + av.y*wb.y + av.z*wb.z + av.w*wb.w;
    }
  }
  float bb0 = bvec[g0], bb1 = bvec[g0+1];
  #pragma unroll
  for (int r=0;r<8;r++) {
    size_t row = (size_t)blk*8 + r;
    xg[row*512 + g0]     = acc0[r] + bb0;
    xg[row*512 + g0 + 1] = acc1[r] + bb1;
  }
}

// ---------------- FRONT: clean enc scan (blocks 0-7) + workers (split + graph) ----
__global__ __launch_bounds__(512) void front_kernel(
    const float* __restrict__ xg, const float* __restrict__ WhhE, float* __restrict__ hmean,
    const float* __restrict__ Wo, __hip_bfloat16* __restrict__ Bhi, __hip_bfloat16* __restrict__ Blo,
    const int* __restrict__ esrc, const int* __restrict__ edst, const int* __restrict__ nids,
    const float* __restrict__ emb,
    float* __restrict__ deg, float* __restrict__ dinv, float* __restrict__ s1,
    float* __restrict__ s2, float* __restrict__ cc, float* __restrict__ ee,
    float* __restrict__ csum, float* __restrict__ gvec,
    const float* __restrict__ W1, const float* __restrict__ b1,
    const float* __restrict__ W2, const float* __restrict__ b2, float* __restrict__ mvec,
    int* bar)
{
  __shared__ __align__(16) char shraw[131072];   // 128KB -> 1 block/CU (isolation)
  const int bid = blockIdx.x, tid = threadIdx.x;

  if (bid < 8) {
    // ---------------- encoder scan role (round-4 proven body) -----------------
    float* h_s   = (float*)shraw;
    float* act_s = ((float*)shraw) + 128;
    const int b = bid;

    const f32x4* Wrow = (const f32x4*)(WhhE + (size_t)tid*HH);
    f32x4 w[32];
    #pragma unroll
    for (int k=0;k<32;k++) w[k] = Wrow[k];
    #pragma unroll
    for (int k=0;k<32;k++) asm volatile("" : "+v"(w[k]));

    const float* xgrow = xg + (size_t)b*SS*512;
    float xv = xgrow[tid];
    if (tid < 128) h_s[tid] = 0.f;
    float cstate = 0.f, hsum = 0.f;
    __syncthreads();

    for (int t=0;t<SS;t++) {
      int tn = (t < SS-1) ? (t+1) : t;
      float nxv = xgrow[(size_t)tn*512 + tid];
      float a0=0.f,a1=0.f,a2=0.f,a3=0.f;
      #pragma unroll
      for (int k=0;k<32;k++) {
        f32x4 hv = *(const f32x4*)&h_s[k*4];
        a0 += w[k].x*hv.x; a1 += w[k].y*hv.y;
        a2 += w[k].z*hv.z; a3 += w[k].w*hv.w;
      }
      float s = (a0+a1)+(a2+a3) + xv;
      int gid = tid >> 7;
      float act = (gid==2) ? tanhf(s) : 1.0f/(1.0f+expf(-s));
      act_s[tid] = act;
      __syncthreads();
      if (tid < 128) {
        float i_ = act_s[tid], f_ = act_s[128+tid], g_ = act_s[256+tid], o_ = act_s[384+tid];
        cstate = f_*cstate + i_*g_;
        float hh = o_*tanhf(cstate);
        h_s[tid] = hh;
        hsum += hh;
      }
      xv = nxv;
      __syncthreads();
    }
    if (tid < 128) hmean[b*HH + tid] = hsum * (1.0f/512.0f);
  } else {
    // ---------------- worker role: Wo split + graph pipeline ------------------
    const int wbid = bid - 8;
    float* red = (float*)shraw;                  // 512 reduce scratch

    // P0: split Wo -> (bf16 hi, lo). nt loads/stores: keep the 32MB stream
    // out of L2 so the scan blocks' W_hh stays resident.
    for (int i = wbid*512 + tid; i < VV*HH/4; i += NWORK*512) {
      f32x4 v = __builtin_nontemporal_load((const f32x4*)&Wo[i*4]);
      float vv[4] = {v.x, v.y, v.z, v.w};
      #pragma unroll
      for (int k=0;k<4;k++) {
        __hip_bfloat16 h = __float2bfloat16(vv[k]);
        float rem = vv[k] - __bfloat162float(h);
        __hip_bfloat16 l = __float2bfloat16(rem);
        __builtin_nontemporal_store(*(unsigned short*)&h, (unsigned short*)&Bhi[i*4+k]);
        __builtin_nontemporal_store(*(unsigned short*)&l, (unsigned short*)&Blo[i*4+k]);
      }
    }
    workers_barrier(bar, tid);
    // P1: degree
    for (int i = wbid*512 + tid; i < NEDGE; i += NWORK*512)
      atomicAdd(&deg[edst[i]], 1.0f);
    workers_barrier(bar, tid);
    // P2: dinv
    for (int n = wbid*512 + tid; n < NNODE; n += NWORK*512)
      dinv[n] = 1.0f / sqrtf(deg[n] + 1.0f);
    workers_barrier(bar, tid);
    // P3: s1
    for (int i = wbid*512 + tid; i < NEDGE; i += NWORK*512)
      atomicAdd(&s1[esrc[i]], dinv[edst[i]]);
    workers_barrier(bar, tid);
    // P4: cc + csum
    {
      float lsum = 0.f;
      for (int n = wbid*512 + tid; n < NNODE; n += NWORK*512) {
        float d = dinv[n]; float v = d*s1[n] + d*d; cc[n] = v; lsum += v;
      }
      red[tid] = lsum; __syncthreads();
      for (int sfl=256; sfl>0; sfl>>=1) { if (tid < sfl) red[tid] += red[tid+sfl]; __syncthreads(); }
      if (tid==0) atomicAdd(csum, red[0]);
    }
    workers_barrier(bar, tid);
    // P5: s2
    for (int i = wbid*512 + tid; i < NEDGE; i += NWORK*512) {
      int d = edst[i]; atomicAdd(&s2[esrc[i]], cc[d]*dinv[d]);
    }
    workers_barrier(bar, tid);
    // P6: ee
    for (int n = wbid*512 + tid; n < NNODE; n += NWORK*512) {
      float d = dinv[n]; ee[n] = d*s2[n] + cc[n]*d*d;
    }
    workers_barrier(bar, tid);
    // P7: gvec[j] = sum_n ee[n]*emb[nids[n]][j]
    {
      int j = tid & 127, sub = tid >> 7;         // 4 n-lanes per block
      float acc = 0.f;
      for (int n = wbid*4 + sub; n < NNODE; n += NWORK*4)
        acc += ee[n] * emb[(size_t)nids[n]*HH + j];
      red[tid] = acc; __syncthreads();
      if (tid < 128) atomicAdd(&gvec[j], red[tid] + red[tid+128] + red[tid+256] + red[tid+384]);
    }
    workers_barrier(bar, tid);
    // P8: graph final (block 0, full-block barriers)
    if (wbid == 0) {
      float* gs = (float*)shraw;
      float* v1 = gs + 128;
      if (tid < 128) gs[tid] = gvec[tid];
      __syncthreads();
      if (tid < 128) {
        float a = 0.f;
        for (int k=0;k<128;k++) a += gs[k]*W1[tid*128+k];
        v1[tid] = a + csum[0]*b1[tid];
      }
      __syncthreads();
      if (tid < 128) {
        float a2 = 0.f;
        for (int k=0;k<128;k++) a2 += v1[k]*W2[tid*128+k];
        mvec[tid] = a2 * (1.0f/(float)NNODE) + b2[tid];
      }
    }
  }
}

// ---------------- FUSED decoder scan + PERSISTENT-owner output GEMM ----------
// Blocks 0-7: decoder scan, publish prog[b*32] every 64 steps. Blocks 8..247:
// persistent owners, B panel staged once in LDS, loop (chunk,batch) tiles.
// Round-17 = round-16 intent: all streaming writes (out, ahi/alo) NON-TEMPORAL
// so they don't write-allocate in L2 and evict the scan blocks' W_hh working
// set (the round-15 interference mechanism).
__global__ __launch_bounds__(512) void dec_gemm_kernel(
    const float* __restrict__ xgdec, const float* __restrict__ Whh,
    __hip_bfloat16* __restrict__ ahi, __hip_bfloat16* __restrict__ alo,
    const __hip_bfloat16* __restrict__ Bhi, const __hip_bfloat16* __restrict__ Blo,
    const float* __restrict__ bo, float* __restrict__ out, int* __restrict__ prog)
{
  __shared__ __align__(16) char shraw[131072];   // 128KB -> 1 block/CU
  const int bid = blockIdx.x, tid = threadIdx.x;

  if (bid < 8) {
    // ---------------- decoder scan role (round-4 body) ----------------
    float* h_s   = (float*)shraw;
    float* act_s = ((float*)shraw) + 128;
    const int b = bid;

    const f32x4* Wrow = (const f32x4*)(Whh + (size_t)tid*HH);
    f32x4 w[32];
    #pragma unroll
    for (int k=0;k<32;k++) w[k] = Wrow[k];
    #pragma unroll
    for (int k=0;k<32;k++) asm volatile("" : "+v"(w[k]));

    float xv = xgdec[b*512 + tid];
    if (tid < 128) h_s[tid] = 0.f;
    float cstate = 0.f;
    __syncthreads();

    for (int t=0;t<SS;t++) {
      float a0=0.f,a1=0.f,a2=0.f,a3=0.f;
      #pragma unroll
      for (int k=0;k<32;k++) {
        f32x4 hv = *(const f32x4*)&h_s[k*4];
        a0 += w[k].x*hv.x; a1 += w[k].y*hv.y;
        a2 += w[k].z*hv.z; a3 += w[k].w*hv.w;
      }
      float s = (a0+a1)+(a2+a3) + xv;
      int gid = tid >> 7;
      float act = (gid==2) ? tanhf(s) : 1.0f/(1.0f+expf(-s));
      act_s[tid] = act;
      __syncthreads();
      if (tid < 128) {
        float i_ = act_s[tid], f_ = act_s[128+tid], g_ = act_s[256+tid], o_ = act_s[384+tid];
        cstate = f_*cstate + i_*g_;
        float hh = o_*tanhf(cstate);
        h_s[tid] = hh;
        size_t row = (size_t)b*SS + t;
        __hip_bfloat16 hi = __float2bfloat16(hh);
        float rem = hh - __bfloat162float(hi);
        __hip_bfloat16 lo = __float2bfloat16(rem);
        __builtin_nontemporal_store(*(unsigned short*)&hi, (unsigned short*)&ahi[row*HH + tid]);
        __builtin_nontemporal_store(*(unsigned short*)&lo, (unsigned short*)&alo[row*HH + tid]);
      }
      __syncthreads();
      if ((t & 63) == 63) {                     // publish completed 64-step chunk
        __threadfence();
        __syncthreads();
        if (tid == 0)
          __hip_atomic_store(&prog[b*32], (t >> 6) + 1,
                             __ATOMIC_RELEASE, __HIP_MEMORY_SCOPE_AGENT);
      }
    }
  } else {
    // ---------------- persistent gemm owner ----------------
    short* smem = (short*)shraw;                // hi plane @0, lo plane @64KB
    const int o = bid - 8;                      // 0..239
    int nblk, b0, nb;
    if (o < 230) { nblk = o >> 1; b0 = (o & 1) * 4; nb = 4; }
    else         { nblk = 115 + (o - 230); b0 = 0; nb = 8; }

    // stage B panel once (256 cols x 128 k, hi+lo), inverse-swizzled source
    const short* bsrc[2] = {
      (const short*)Bhi + (size_t)nblk*256*HH,
      (const short*)Blo + (size_t)nblk*256*HH };
    #pragma unroll
    for (int p=0;p<2;p++) {
      #pragma unroll
      for (int it=0; it<8; it++) {
        int off  = it*8192 + tid*16;
        int row  = off >> 8;
        int soff = off ^ ((row & 15) << 4);
        __builtin_amdgcn_global_load_lds(
          (const __attribute__((address_space(1))) void*)((const char*)bsrc[p] + soff),
          (__attribute__((address_space(3))) void*)((char*)smem + p*65536 + off),
          16, 0, 0);
      }
    }
    __syncthreads();

    const int lane = tid & 63;
    const int wid  = tid >> 6;
    const int wm = wid >> 2, wn = wid & 3;      // 2m x 4n waves: 32x64 each
    const int l15 = lane & 15, l4 = lane >> 4;
    const short* Ah = (const short*)ahi;
    const short* Al = (const short*)alo;

    for (int c = 0; c < 8; ++c) {
      for (int bi = 0; bi < nb; ++bi) {
        int b = b0 + bi;
        if (tid == 0) {                         // single-lane, slow poll
          while (__hip_atomic_load(&prog[b*32], __ATOMIC_ACQUIRE,
                                   __HIP_MEMORY_SCOPE_AGENT) <= c)
            __builtin_amdgcn_s_sleep(64);
        }
        __syncthreads();

        const int mbase = b*512 + c*64 + wm*32;
        f32x4 acc[2][4] = {};
        #pragma unroll
        for (int s=0;s<4;s++) {
          s16x8 bh[4], bl[4], ah[2], al[2];
          #pragma unroll
          for (int qn=0;qn<4;qn++) {
            int rb   = wn*64 + qn*16 + l15;
            int offb = (rb*256 + s*64 + l4*16) ^ ((rb & 15) << 4);
            bh[qn] = *(const s16x8*)((const char*)smem + offb);
            bl[qn] = *(const s16x8*)((const char*)smem + 65536 + offb);
          }
          #pragma unroll
          for (int qm=0;qm<2;qm++) {
            int arow = mbase + qm*16 + l15;
            size_t aoff = (size_t)arow*HH + s*32 + l4*8;
            ah[qm] = *(const s16x8*)(Ah + aoff);    // A normal loads (want L2/L3 reuse)
            al[qm] = *(const s16x8*)(Al + aoff);
          }
          #pragma unroll
          for (int qm=0;qm<2;qm++) {
            #pragma unroll
            for (int qn=0;qn<4;qn++) {
              acc[qm][qn] = __builtin_amdgcn_mfma_f32_16x16x32_bf16(bh[qn], ah[qm], acc[qm][qn], 0,0,0);
              acc[qm][qn] = __builtin_amdgcn_mfma_f32_16x16x32_bf16(bl[qn], ah[qm], acc[qm][qn], 0,0,0);
              acc[qm][qn] = __builtin_amdgcn_mfma_f32_16x16x32_bf16(bh[qn], al[qm], acc[qm][qn], 0,0,0);
            }
          }
        }
        #pragma unroll
        for (int qm=0;qm<2;qm++) {
          int row = mbase + qm*16 + l15;        // swapped C/D: l15 = M-row
          #pragma unroll
          for (int qn=0;qn<4;qn++) {
            int colb = nblk*256 + wn*64 + qn*16 + l4*4;
            f32x4 bv = *(const f32x4*)&bo[colb];
            f32x4 oo = acc[qm][qn] + bv;
            // nt store: 512MB stream must not evict scan weights from L2
            __builtin_nontemporal_store(oo, (f32x4*)&out[(size_t)row*VV + colb]);
          }
        }
      }
    }
  }
}

// ---------------- fusion ----------------
__global__ __launch_bounds__(512) void fusion_kernel(const float* __restrict__ hmean, const float* __restrict__ mvec,
    const float* __restrict__ Wf, const float* __restrict__ bfv,
    const float* __restrict__ Wihd, const float* __restrict__ bd, float* __restrict__ xgdec)
{
  __shared__ float comb[256];
  __shared__ float fus[128];
  int b = blockIdx.x, tid = threadIdx.x;
  if (tid < 128) comb[tid] = hmean[b*128 + tid];
  else if (tid < 256) comb[tid] = mvec[tid - 128];
  __syncthreads();
  if (tid < 128) {
    float a = 0.f;
    for (int k=0;k<256;k++) a += comb[k]*Wf[tid*256+k];
    fus[tid] = a + bfv[tid];
  }
  __syncthreads();
  float a = 0.f;
  for (int k=0;k<128;k++) a += fus[k]*Wihd[tid*128+k];
  xgdec[b*512 + tid] = a + bd[tid];
}

// ---------------- launch ----------------
extern "C" void kernel_launch(void* const* d_in, const int* in_sizes, int n_in,
                              void* d_out, int out_size, void* d_ws, size_t ws_size,
                              hipStream_t stream)
{
  (void)in_sizes; (void)n_in; (void)out_size; (void)ws_size;
  const int*   jin   = (const int*)d_in[0];
  const int*   nids  = (const int*)d_in[1];
  const int*   esrc  = (const int*)d_in[2];
  const int*   edst  = esrc + NEDGE;
  const float* emb   = (const float*)d_in[3];
  const float* WihE  = (const float*)d_in[4];
  const float* WhhE  = (const float*)d_in[5];
  const float* bE    = (const float*)d_in[6];
  const float* W1    = (const float*)d_in[7];
  const float* b1    = (const float*)d_in[8];
  const float* W2    = (const float*)d_in[9];
  const float* b2    = (const float*)d_in[10];
  const float* Wf    = (const float*)d_in[11];
  const float* bfv   = (const float*)d_in[12];
  const float* WihD  = (const float*)d_in[13];
  const float* WhhD  = (const float*)d_in[14];
  const float* bD    = (const float*)d_in[15];
  const float* Wo    = (const float*)d_in[16];
  const float* bo    = (const float*)d_in[17];
  float* out = (float*)d_out;

  char* ws = (char*)d_ws;
  size_t off = 0;
  auto alloc = [&](size_t bytes) { size_t o = off; off = (off + bytes + 255) & ~(size_t)255; return o; };

  int*   prog = (int*)(ws + alloc(BB*32*4));       // decoder progress (line/batch)
  int*   bar  = (int*)(ws + alloc(64*4));          // workers barrier cnt/gen
  float* deg  = (float*)(ws + alloc(NNODE*4));
  float* s1   = (float*)(ws + alloc(NNODE*4));
  float* s2   = (float*)(ws + alloc(NNODE*4));
  float* gvec = (float*)(ws + alloc(128*4));
  float* csum = (float*)(ws + alloc(4));
  size_t zero_bytes = off;
  float* dinv = (float*)(ws + alloc(NNODE*4));
  float* cc   = (float*)(ws + alloc(NNODE*4));
  float* ee   = (float*)(ws + alloc(NNODE*4));
  float* mvec = (float*)(ws + alloc(128*4));
  float* hmean= (float*)(ws + alloc(BB*HH*4));
  float* xgdec= (float*)(ws + alloc(BB*512*4));
  float* xgenc= (float*)(ws + alloc((size_t)BB*SS*512*4));
  __hip_bfloat16* Ahi = (__hip_bfloat16*)(ws + alloc((size_t)BB*SS*HH*2));
  __hip_bfloat16* Alo = (__hip_bfloat16*)(ws + alloc((size_t)BB*SS*HH*2));
  __hip_bfloat16* Bhi = (__hip_bfloat16*)(ws + alloc((size_t)VV*HH*2));
  __hip_bfloat16* Blo = (__hip_bfloat16*)(ws + alloc((size_t)VV*HH*2));

  hipMemsetAsync(ws, 0, zero_bytes, stream);

  // serial xg production (tiny, ~20us)
  xg_enc_kernel<<<dim3((BB*SS)/8), dim3(256), 0, stream>>>(jin, emb, WihE, bE, xgenc);

  // front: clean enc scan + {Wo split, graph pipeline} on idle CUs
  front_kernel<<<dim3(8 + NWORK), dim3(512), 0, stream>>>(
      xgenc, WhhE, hmean, Wo, Bhi, Blo,
      esrc, edst, nids, emb, deg, dinv, s1, s2, cc, ee, csum, gvec,
      W1, b1, W2, b2, mvec, bar);

  // fusion, then fused decoder-scan + persistent-owner GEMM
  fusion_kernel<<<dim3(BB), dim3(512), 0, stream>>>(hmean, mvec, Wf, bfv, WihD, bD, xgdec);
  dec_gemm_kernel<<<dim3(8 + NWORK), dim3(512), 0, stream>>>(
      xgdec, WhhD, Ahi, Alo, Bhi, Blo, bo, out, prog);
}